// Round 2
// baseline (16930.191 us; speedup 1.0000x reference)
//
#include <hip/hip_runtime.h>
#include <hip/hip_bf16.h>
#include <math.h>

// ---------------- problem constants ----------------
#define Bsz 512
#define Tin 96
#define DIN 64
#define Hd  256
#define Pp  2
#define Ll  4
#define NHEAD 8
#define Ed  768          // 3*H
#define NCls 100
#define Tp  48           // T/P tokens after patch
#define Ff  25           // rfft freqs of 48
#define F2  13           // rfft freqs of 25
#define DH  96           // E / HEADS

// epilogue flags
#define E_BIAS 1
#define E_PE   2
#define E_RES  4
#define E_ACC  8
#define E_GELU 16

// A modes
// 0 = plain row-major [M,K] (ld=Ald)
// 1 = diff along token dim (Tdim): a = h[row]-h[row-1], 0 at t==0
// 2 = conv tap-shift: row=(b,t), kk=(i*ntaps+tap), a = A[b, t-lo+tap, i] or 0
// B modes: 0 = [K,N] row-major ; 1 = [N,K] row-major (conv [O,I,k] flattened)

constexpr int BM = 64, BN = 64, BK = 16, TM = 4, TN = 4;

template<int AMODE, int BMODE, int EPI>
__global__ __launch_bounds__(256) void gemm_k(
    const float* __restrict__ A, const float* __restrict__ Bw,
    const float* __restrict__ bias, const float* __restrict__ extra,
    float* __restrict__ C,
    int M, int N, int K,
    int Ald, int Tdim, int ntaps, int lo, int Cld, int coff)
{
  __shared__ alignas(16) float As[BK][BM + 4];
  __shared__ alignas(16) float Bs[BK][BN + 4];
  int tid = threadIdx.x;
  int n0 = blockIdx.x * BN;
  int m0 = blockIdx.y * BM;
  int tx = tid & 15, ty = tid >> 4;

  float acc[TM][TN];
#pragma unroll
  for (int i = 0; i < TM; i++)
#pragma unroll
    for (int j = 0; j < TN; j++) acc[i][j] = 0.0f;

  int a_m = tid >> 2;          // 0..63
  int a_k = (tid & 3) * 4;     // 0,4,8,12
  int b_k = tid >> 4;          // 0..15
  int b_n = (tid & 15) * 4;    // 0..60

  for (int k0 = 0; k0 < K; k0 += BK) {
    // ---- load A tile (64 x 16) ----
    {
      int row = m0 + a_m;
#pragma unroll
      for (int j = 0; j < 4; j++) {
        int kk = k0 + a_k + j;
        float v;
        if (AMODE == 0) {
          v = A[(size_t)row * Ald + kk];
        } else if (AMODE == 1) {
          int t = row % Tdim;
          v = (t == 0) ? 0.0f
                       : (A[(size_t)row * Ald + kk] - A[(size_t)(row - 1) * Ald + kk]);
        } else {
          int bb = row / Tdim;
          int t  = row - bb * Tdim;
          int i2  = kk / ntaps;
          int tap = kk - i2 * ntaps;
          int tt = t - lo + tap;
          v = (tt >= 0 && tt < Tdim) ? A[((size_t)bb * Tdim + tt) * Ald + i2] : 0.0f;
        }
        As[a_k + j][a_m] = v;
      }
    }
    // ---- load B tile (16 x 64) ----
    {
      int kk = k0 + b_k;
#pragma unroll
      for (int j = 0; j < 4; j++) {
        int nn = n0 + b_n + j;
        float v = 0.0f;
        if (nn < N) {
          if (BMODE == 0) v = Bw[(size_t)kk * N + nn];
          else            v = Bw[(size_t)nn * K + kk];
        }
        Bs[b_k][b_n + j] = v;
      }
    }
    __syncthreads();
#pragma unroll
    for (int k = 0; k < BK; k++) {
      float4 av = *reinterpret_cast<const float4*>(&As[k][ty * TM]);
      float4 bv = *reinterpret_cast<const float4*>(&Bs[k][tx * TN]);
      float a4[4] = {av.x, av.y, av.z, av.w};
      float b4[4] = {bv.x, bv.y, bv.z, bv.w};
#pragma unroll
      for (int i = 0; i < TM; i++)
#pragma unroll
        for (int j = 0; j < TN; j++)
          acc[i][j] += a4[i] * b4[j];
    }
    __syncthreads();
  }

  // ---- epilogue ----
#pragma unroll
  for (int i = 0; i < TM; i++) {
    int row = m0 + ty * TM + i;
#pragma unroll
    for (int j = 0; j < TN; j++) {
      int col = n0 + tx * TN + j;
      if (col >= N) continue;
      float v = acc[i][j];
      if (EPI & E_BIAS) v += bias[col];
      if (EPI & E_PE)   v += extra[(size_t)(row % Tdim) * N + col];
      if (EPI & E_RES)  v += extra[(size_t)row * Cld + col];
      if (EPI & E_GELU) v = 0.5f * v * (1.0f + erff(v * 0.70710678118654752f));
      float* cp = C + (size_t)row * Cld + coff + col;
      if (EPI & E_ACC) v += *cp;
      *cp = v;
    }
  }
}

// ---- rfft over 48 tokens, real part ----
__global__ __launch_bounds__(256) void rfft48_kernel(
    const float* __restrict__ hp, float* __restrict__ f)
{
  int kf = blockIdx.x;   // 0..24
  int b  = blockIdx.y;   // local batch
  int tid = threadIdx.x; // channel
  __shared__ float ct[48];
  if (tid < 48) {
    int r = (kf * tid) % 48;
    ct[tid] = cosf(6.2831853071795864f * (float)r / 48.0f);
  }
  __syncthreads();
  const float* hb = hp + (size_t)b * Tp * Hd;
  float s = 0.0f;
  for (int t = 0; t < 48; t++) s += hb[t * Hd + tid] * ct[t];
  f[((size_t)b * Ff + kf) * Hd + tid] = s;
}

// ---- fourier attention logits + softmax; one block per (b,head) ----
__global__ __launch_bounds__(128) void attn_kernel(
    const float* __restrict__ qkv, float* __restrict__ attnw)
{
  int bh = blockIdx.x;
  int b = bh >> 3, h = bh & 7;
  __shared__ float qs[Ff * DH], ks2[Ff * DH];
  __shared__ float ct[F2 * Ff], st[F2 * Ff];
  __shared__ float red[F2][DH];
  __shared__ float sm[F2];
  int tid = threadIdx.x;
  const float* base = qkv + (size_t)b * Ff * (3 * Ed) + h * DH;
  for (int e = tid; e < Ff * DH; e += 128) {
    int t = e / DH, d = e - t * DH;
    qs[e]  = base[(size_t)t * (3 * Ed) + d];
    ks2[e] = base[(size_t)t * (3 * Ed) + Ed + d];
  }
  for (int e = tid; e < F2 * Ff; e += 128) {
    int fq = e / Ff, t = e - fq * Ff;
    int r = (fq * t) % Ff;
    float ang = 6.2831853071795864f * (float)r / 25.0f;
    ct[e] = cosf(ang); st[e] = sinf(ang);
  }
  __syncthreads();
  if (tid < DH) {
    int d = tid;
    for (int fq = 0; fq < F2; fq++) {
      float qr = 0, qi = 0, kr = 0, ki = 0;
      for (int t = 0; t < Ff; t++) {
        float c = ct[fq * Ff + t], s = st[fq * Ff + t];
        float qv = qs[t * DH + d], kv = ks2[t * DH + d];
        qr += qv * c; qi += qv * s; kr += kv * c; ki += kv * s;
      }
      red[fq][d] = qr * kr + qi * ki;
    }
  }
  __syncthreads();
  if (tid < F2) {
    float s = 0;
    for (int d = 0; d < DH; d++) s += red[tid][d];
    sm[tid] = s * 0.10206207261596575f;  // 96^-0.5
  }
  __syncthreads();
  if (tid == 0) {
    float mx = sm[0];
    for (int fq = 1; fq < F2; fq++) mx = fmaxf(mx, sm[fq]);
    float den = 0;
    for (int fq = 0; fq < F2; fq++) { float e = expf(sm[fq] - mx); sm[fq] = e; den += e; }
    float inv = 1.0f / den;
    for (int fq = 0; fq < F2; fq++) sm[fq] *= inv;
  }
  __syncthreads();
  if (tid < F2) attnw[(size_t)bh * F2 + tid] = sm[tid];
}

// ---- v -> vf, scale by attn, irfft(n=25); one block per (b,head) ----
__global__ __launch_bounds__(128) void virfft_kernel(
    const float* __restrict__ qkv, const float* __restrict__ attnw,
    float* __restrict__ out)
{
  int bh = blockIdx.x;
  int b = bh >> 3, h = bh & 7;
  __shared__ float vs[Ff * DH];
  __shared__ float Vr[F2 * DH], Vi[F2 * DH];
  __shared__ float ct[F2 * Ff], st[F2 * Ff];
  __shared__ float af[F2];
  int tid = threadIdx.x;
  const float* vbase = qkv + (size_t)b * Ff * (3 * Ed) + 2 * Ed + h * DH;
  for (int e = tid; e < Ff * DH; e += 128) {
    int t = e / DH, d = e - t * DH;
    vs[e] = vbase[(size_t)t * (3 * Ed) + d];
  }
  for (int e = tid; e < F2 * Ff; e += 128) {
    int fq = e / Ff, t = e - fq * Ff;
    int r = (fq * t) % Ff;
    float ang = 6.2831853071795864f * (float)r / 25.0f;
    ct[e] = cosf(ang); st[e] = sinf(ang);
  }
  if (tid < F2)
    af[tid] = attnw[(size_t)bh * F2 + tid] * ((tid == 0) ? (1.0f / 25.0f) : (2.0f / 25.0f));
  __syncthreads();
  for (int e = tid; e < F2 * DH; e += 128) {
    int fq = e / DH, d = e - fq * DH;
    float vr = 0, vi = 0;
    for (int t = 0; t < Ff; t++) {
      float vv = vs[t * DH + d];
      vr += vv * ct[fq * Ff + t];
      vi -= vv * st[fq * Ff + t];
    }
    Vr[e] = vr; Vi[e] = vi;
  }
  __syncthreads();
  float* obase = out + (size_t)b * Ff * Ed + h * DH;
  for (int e = tid; e < Ff * DH; e += 128) {
    int t = e / DH, d = e - t * DH;
    float o = 0;
    for (int fq = 0; fq < F2; fq++)
      o += af[fq] * (ct[fq * Ff + t] * Vr[fq * DH + d] - st[fq * Ff + t] * Vi[fq * DH + d]);
    obase[(size_t)t * Ed + d] = o;
  }
}

// ---- layernorm over last dim 768 ----
__global__ __launch_bounds__(256) void ln_kernel(
    const float* __restrict__ x, const float* __restrict__ g,
    const float* __restrict__ bb, float* __restrict__ y)
{
  int row = blockIdx.x;
  int tid = threadIdx.x;
  const float* xr = x + (size_t)row * Ed;
  float v0 = xr[tid], v1 = xr[tid + 256], v2 = xr[tid + 512];
  __shared__ float rs[256];
  rs[tid] = v0 + v1 + v2;
  __syncthreads();
  for (int o = 128; o > 0; o >>= 1) {
    if (tid < o) rs[tid] += rs[tid + o];
    __syncthreads();
  }
  float m = rs[0] * (1.0f / 768.0f);
  __syncthreads();
  float d0 = v0 - m, d1 = v1 - m, d2 = v2 - m;
  rs[tid] = d0 * d0 + d1 * d1 + d2 * d2;
  __syncthreads();
  for (int o = 128; o > 0; o >>= 1) {
    if (tid < o) rs[tid] += rs[tid + o];
    __syncthreads();
  }
  float inv = rsqrtf(rs[0] * (1.0f / 768.0f) + 1e-5f);
  float* yr = y + (size_t)row * Ed;
  yr[tid]       = d0 * inv * g[tid]       + bb[tid];
  yr[tid + 256] = d1 * inv * g[tid + 256] + bb[tid + 256];
  yr[tid + 512] = d2 * inv * g[tid + 512] + bb[tid + 512];
}

// ---- mean over 25 tokens ----
__global__ __launch_bounds__(256) void mean_kernel(
    const float* __restrict__ x, float* __restrict__ y)
{
  int b = blockIdx.x;
  int tid = threadIdx.x;
  for (int c = tid; c < Ed; c += 256) {
    float s = 0;
    for (int t = 0; t < Ff; t++) s += x[((size_t)b * Ff + t) * Ed + c];
    y[(size_t)b * Ed + c] = s * (1.0f / 25.0f);
  }
}

extern "C" void kernel_launch(void* const* d_in, const int* in_sizes, int n_in,
                              void* d_out, int out_size, void* d_ws, size_t ws_size,
                              hipStream_t stream)
{
  const float* x       = (const float*)d_in[0];
  const float* W_in    = (const float*)d_in[1];
  const float* b_in    = (const float*)d_in[2];
  const float* pe      = (const float*)d_in[3];
  const float* W_shape = (const float*)d_in[4];
  const float* b_shape = (const float*)d_in[5];
  const float* W_patch = (const float*)d_in[6];
  const float* b_patch = (const float*)d_in[7];
  const float* conv_w1 = (const float*)d_in[8];
  const float* conv_b1 = (const float*)d_in[9];
  const float* conv_w2 = (const float*)d_in[10];
  const float* conv_b2 = (const float*)d_in[11];
  const float* conv_w4 = (const float*)d_in[12];
  const float* conv_b4 = (const float*)d_in[13];
  const float* ln1_g   = (const float*)d_in[14];
  const float* ln1_b   = (const float*)d_in[15];
  const float* Wqkv    = (const float*)d_in[16];
  const float* Wo      = (const float*)d_in[17];
  const float* bo      = (const float*)d_in[18];
  const float* ln2_g   = (const float*)d_in[19];
  const float* ln2_b   = (const float*)d_in[20];
  const float* Wf1     = (const float*)d_in[21];
  const float* bf1     = (const float*)d_in[22];
  const float* Wf2     = (const float*)d_in[23];
  const float* bf2     = (const float*)d_in[24];
  const float* ssm_w   = (const float*)d_in[25];
  const float* ssm_b   = (const float*)d_in[26];
  const float* ssm_g   = (const float*)d_in[27];
  const float* ssm_bn  = (const float*)d_in[28];
  const float* W_out   = (const float*)d_in[29];
  const float* b_out   = (const float*)d_in[30];
  float* out = (float*)d_out;

  // ---- workspace: 3 arenas of 9,830,400 floats + small region = ~114 MiB ----
  constexpr size_t ASZ = 9830400;   // 12800*768
  float* A0 = (float*)d_ws;         // lnout / phase0 scratch
  float* A1 = A0 + ASZ;             // persistent h [12800,768]
  float* A2 = A1 + ASZ;             // chunk buffer (qkv / ffmid / h2 / f)
  float* A3 = A2 + ASZ;             // attnw (65536) + mean (393216)
  float* attnw_ws = A3;
  float* mean_ws  = A3 + 65536;

  dim3 blk(256);
  const int Mf  = Bsz * Ff;    // 12800

  // ================= phase 0: chunked by 256 batches (2 chunks) =============
  for (int c = 0; c < 2; c++) {
    const int NB   = 256;                 // batches in chunk
    const int M96  = NB * Tin;            // 24576
    const int Mpch = NB * Tp;             // 12288
    const int Mfch = NB * Ff;             // 6400
    const float* xc = x + (size_t)c * NB * Tin * DIN;

    // 1) h = x @ W_in + b_in + pe           -> A0 [24576,256]
    gemm_k<0, 0, E_BIAS | E_PE><<<dim3(Hd / BN, M96 / BM), blk, 0, stream>>>(
        xc, W_in, b_in, pe, A0, M96, Hd, DIN, DIN, Tin, 0, 0, Hd, 0);

    // 2) h2 = h + diff(h) @ W_shape + b_shape  -> A2 [24576,256]
    gemm_k<1, 0, E_BIAS | E_RES><<<dim3(Hd / BN, M96 / BM), blk, 0, stream>>>(
        A0, W_shape, b_shape, A0, A2, M96, Hd, Hd, Hd, Tin, 0, 0, Hd, 0);

    // 3) patch: A2 viewed [12288,512] @ W_patch -> A0 (hp [NB,48,256])
    gemm_k<0, 0, E_BIAS><<<dim3(Hd / BN, Mpch / BM), blk, 0, stream>>>(
        A2, W_patch, b_patch, nullptr, A0, Mpch, Hd, Pp * Hd, Pp * Hd, 0, 0, 0, Hd, 0);

    // 4) rfft real part A0 -> A2 (f [NB,25,256])
    rfft48_kernel<<<dim3(Ff, NB), blk, 0, stream>>>(A0, A2);

    // 5) multiscale convs: A2 -> h rows in A1
    float* hrows = A1 + (size_t)c * Mfch * Ed;
    gemm_k<2, 1, E_BIAS><<<dim3(Hd / BN, Mfch / BM), blk, 0, stream>>>(
        A2, conv_w1, conv_b1, nullptr, hrows, Mfch, Hd, Hd * 1, Hd, Ff, 1, 0, Ed, 0);
    gemm_k<2, 1, E_BIAS><<<dim3(Hd / BN, Mfch / BM), blk, 0, stream>>>(
        A2, conv_w2, conv_b2, nullptr, hrows, Mfch, Hd, Hd * 2, Hd, Ff, 2, 0, Ed, Hd);
    gemm_k<2, 1, E_BIAS><<<dim3(Hd / BN, Mfch / BM), blk, 0, stream>>>(
        A2, conv_w4, conv_b4, nullptr, hrows, Mfch, Hd, Hd * 4, Hd, Ff, 4, 1, Ed, 2 * Hd);
  }

  // ================= transformer layers (h in A1) ===========================
  const int NBC = 128;            // batches per layer chunk (4 chunks)
  const int Mch = NBC * Ff;       // 3200 rows
  for (int l = 0; l < Ll; l++) {
    const float* Wqkv_l = Wqkv + (size_t)l * Ed * (3 * Ed);
    const float* Wo_l   = Wo   + (size_t)l * Ed * Ed;
    const float* bo_l   = bo   + (size_t)l * Ed;
    const float* Wf1_l  = Wf1  + (size_t)l * Ed * (4 * Ed);
    const float* bf1_l  = bf1  + (size_t)l * (4 * Ed);
    const float* Wf2_l  = Wf2  + (size_t)l * (4 * Ed) * Ed;
    const float* bf2_l  = bf2  + (size_t)l * Ed;

    // ln1: A1 -> A0 (full)
    ln_kernel<<<Mf, blk, 0, stream>>>(A1, ln1_g + (size_t)l * Ed, ln1_b + (size_t)l * Ed, A0);

    // attention, chunked by 128 batches; virfft writes in-place over A0 rows
    for (int c = 0; c < 4; c++) {
      float* rows = A0 + (size_t)c * Mch * Ed;
      gemm_k<0, 0, 0><<<dim3(3 * Ed / BN, Mch / BM), blk, 0, stream>>>(
          rows, Wqkv_l, nullptr, nullptr, A2, Mch, 3 * Ed, Ed, Ed, 0, 0, 0, 3 * Ed, 0);
      attn_kernel<<<NBC * NHEAD, dim3(128), 0, stream>>>(A2, attnw_ws);
      virfft_kernel<<<NBC * NHEAD, dim3(128), 0, stream>>>(A2, attnw_ws, rows);
    }
    // Wo projection + residual accumulate into h (A1)
    gemm_k<0, 0, E_BIAS | E_ACC><<<dim3(Ed / BN, Mf / BM), blk, 0, stream>>>(
        A0, Wo_l, bo_l, nullptr, A1, Mf, Ed, Ed, Ed, 0, 0, 0, Ed, 0);

    // ln2: A1 -> A0 (full)
    ln_kernel<<<Mf, blk, 0, stream>>>(A1, ln2_g + (size_t)l * Ed, ln2_b + (size_t)l * Ed, A0);

    // FF, chunked by 128 batches through A2
    for (int c = 0; c < 4; c++) {
      float* rows  = A0 + (size_t)c * Mch * Ed;
      float* hrows = A1 + (size_t)c * Mch * Ed;
      gemm_k<0, 0, E_BIAS | E_GELU><<<dim3(4 * Ed / BN, Mch / BM), blk, 0, stream>>>(
          rows, Wf1_l, bf1_l, nullptr, A2, Mch, 4 * Ed, Ed, Ed, 0, 0, 0, 4 * Ed, 0);
      gemm_k<0, 0, E_BIAS | E_ACC><<<dim3(Ed / BN, Mch / BM), blk, 0, stream>>>(
          A2, Wf2_l, bf2_l, nullptr, hrows, Mch, Ed, 4 * Ed, 4 * Ed, 0, 0, 0, Ed, 0);
    }
  }

  // ================= tail ====================================================
  // ssm conv (k=3, same) + residual -> A0 = h + s
  gemm_k<2, 1, E_BIAS | E_RES><<<dim3(Ed / BN, Mf / BM), blk, 0, stream>>>(
      A1, ssm_w, ssm_b, A1, A0, Mf, Ed, Ed * 3, Ed, Ff, 3, 1, Ed, 0);

  // final layernorm -> A2
  ln_kernel<<<Mf, blk, 0, stream>>>(A0, ssm_g, ssm_bn, A2);

  // mean over tokens -> mean_ws [512,768]
  mean_kernel<<<Bsz, blk, 0, stream>>>(A2, mean_ws);

  // classifier: [512,768] @ [768,100] + b_out -> out
  gemm_k<0, 0, E_BIAS><<<dim3(2, Bsz / BM), blk, 0, stream>>>(
      mean_ws, W_out, b_out, nullptr, out, Bsz, NCls, Ed, Ed, 0, 0, 0, NCls, 0);
}

// Round 4
// 10224.495 us; speedup vs baseline: 1.6558x; 1.6558x over previous
//
#include <hip/hip_runtime.h>
#include <hip/hip_bf16.h>
#include <math.h>

// ---------------- problem constants ----------------
#define Bsz 512
#define Tin 96
#define DIN 64
#define Hd  256
#define Pp  2
#define Ll  4
#define NHEAD 8
#define Ed  768          // 3*H
#define NCls 100
#define Tp  48           // T/P tokens after patch
#define Ff  25           // rfft freqs of 48
#define F2  13           // rfft freqs of 25
#define DH  96           // E / HEADS

// epilogue flags
#define E_BIAS 1
#define E_PE   2
#define E_RES  4
#define E_ACC  8
#define E_GELU 16

typedef unsigned short ushortT;
typedef unsigned short ushort8 __attribute__((ext_vector_type(8)));
typedef short short8 __attribute__((ext_vector_type(8)));
typedef float f32x4 __attribute__((ext_vector_type(4)));

static __device__ __forceinline__ ushortT f2bf(float f) {
  __hip_bfloat16 h = __float2bfloat16(f);
  return *reinterpret_cast<ushortT*>(&h);
}
static __device__ __forceinline__ float bfbits2f(ushortT u) {
  unsigned int x = ((unsigned int)u) << 16;
  return __uint_as_float(x);
}
static __device__ __forceinline__ void split2(float v, ushortT& h, ushortT& l) {
  h = f2bf(v);
  l = f2bf(v - bfbits2f(h));
}

// =================== bf16x3 split MFMA GEMM ===================
// A: fp32 [M,K] row-major (ld=Ald). AMODE 0 plain; 1 diff along Tdim; 2 conv gather (NT taps).
// B: pre-split bf16 hi/lo, [N][K] row-major.
// C: fp32, ld=Cld, +coff. acc = Ah*Bh + Al*Bh + Ah*Bl (fp32-grade product).
constexpr int GBM = 128, GBN = 128, GBK = 32, LDK = GBK + 8;

template<int AMODE, int EPI, int NT>
__global__ __launch_bounds__(256) void gemm3(
    const float* __restrict__ A,
    const ushortT* __restrict__ Bh, const ushortT* __restrict__ Bl,
    const float* __restrict__ bias, const float* __restrict__ extra,
    float* __restrict__ C,
    int M, int N, int K, int Ald, int Tdim, int lo, int Cld, int coff)
{
  __shared__ ushortT Ash[GBM * LDK];
  __shared__ ushortT Asl[GBM * LDK];
  __shared__ ushortT Bsh[GBN * LDK];
  __shared__ ushortT Bsl[GBN * LDK];
  int tid = threadIdx.x;
  int m0 = blockIdx.y * GBM, n0 = blockIdx.x * GBN;
  int wid = tid >> 6, lane = tid & 63;
  int wm = wid & 1, wn = wid >> 1;
  int m16 = lane & 15, quad = lane >> 4;

  f32x4 acc[4][4] = {};

  int srow = tid >> 1;           // 0..127
  int skh  = (tid & 1) * 16;     // 0 or 16

  for (int k0 = 0; k0 < K; k0 += GBK) {
    // ---- stage A: 16 fp32 -> split to hi/lo bf16 ----
    {
      float tf[16];
      int row = m0 + srow;
      if (row >= M) row = M - 1;           // clamp (epilogue guards writes)
      if (AMODE == 0) {
        const float* p = A + (size_t)row * Ald + k0 + skh;
#pragma unroll
        for (int j = 0; j < 16; j += 4) {
          float4 v = *(const float4*)(p + j);
          tf[j] = v.x; tf[j+1] = v.y; tf[j+2] = v.z; tf[j+3] = v.w;
        }
      } else if (AMODE == 1) {
        int t = row % Tdim;
        const float* p = A + (size_t)row * Ald + k0 + skh;
#pragma unroll
        for (int j = 0; j < 16; j += 4) {
          float4 v = *(const float4*)(p + j);
          float4 w = (t != 0) ? *(const float4*)(p - Ald + j) : v;
          tf[j] = v.x - w.x; tf[j+1] = v.y - w.y;
          tf[j+2] = v.z - w.z; tf[j+3] = v.w - w.w;
        }
      } else {   // conv gather
        int bb = row / Tdim;
        int t  = row - bb * Tdim;
        const float* Abase = A + (size_t)bb * Tdim * Ald;
#pragma unroll
        for (int j = 0; j < 16; j++) {
          int kk = k0 + skh + j;
          int i2 = kk / NT;
          int tap = kk - i2 * NT;
          int tt = t - lo + tap;
          tf[j] = (tt >= 0 && tt < Tdim) ? Abase[(size_t)tt * Ald + i2] : 0.0f;
        }
      }
      ushortT th[16], tl[16];
#pragma unroll
      for (int j = 0; j < 16; j++) split2(tf[j], th[j], tl[j]);
      *(ushort8*)&Ash[srow * LDK + skh]     = *(ushort8*)&th[0];
      *(ushort8*)&Ash[srow * LDK + skh + 8] = *(ushort8*)&th[8];
      *(ushort8*)&Asl[srow * LDK + skh]     = *(ushort8*)&tl[0];
      *(ushort8*)&Asl[srow * LDK + skh + 8] = *(ushort8*)&tl[8];
    }
    // ---- stage B hi/lo ----
    {
      size_t boff = (size_t)(n0 + srow) * K + k0 + skh;
      *(uint4*)&Bsh[srow * LDK + skh]     = *(const uint4*)(Bh + boff);
      *(uint4*)&Bsh[srow * LDK + skh + 8] = *(const uint4*)(Bh + boff + 8);
      *(uint4*)&Bsl[srow * LDK + skh]     = *(const uint4*)(Bl + boff);
      *(uint4*)&Bsl[srow * LDK + skh + 8] = *(const uint4*)(Bl + boff + 8);
    }
    __syncthreads();
    short8 ah[4], al[4], bh[4], bl[4];
#pragma unroll
    for (int i = 0; i < 4; i++) {
      int ro = (wm * 64 + i * 16 + m16) * LDK + quad * 8;
      ah[i] = *(short8*)&Ash[ro];
      al[i] = *(short8*)&Asl[ro];
    }
#pragma unroll
    for (int j = 0; j < 4; j++) {
      int ro = (wn * 64 + j * 16 + m16) * LDK + quad * 8;
      bh[j] = *(short8*)&Bsh[ro];
      bl[j] = *(short8*)&Bsl[ro];
    }
#pragma unroll
    for (int i = 0; i < 4; i++)
#pragma unroll
      for (int j = 0; j < 4; j++) {
        acc[i][j] = __builtin_amdgcn_mfma_f32_16x16x32_bf16(ah[i], bh[j], acc[i][j], 0, 0, 0);
        acc[i][j] = __builtin_amdgcn_mfma_f32_16x16x32_bf16(al[i], bh[j], acc[i][j], 0, 0, 0);
        acc[i][j] = __builtin_amdgcn_mfma_f32_16x16x32_bf16(ah[i], bl[j], acc[i][j], 0, 0, 0);
      }
    __syncthreads();
  }

  // ---- epilogue: C/D map col=lane&15, row=quad*4+r ----
#pragma unroll
  for (int i = 0; i < 4; i++) {
#pragma unroll
    for (int j = 0; j < 4; j++) {
      int colg = n0 + wn * 64 + j * 16 + m16;
#pragma unroll
      for (int r = 0; r < 4; r++) {
        int rowg = m0 + wm * 64 + i * 16 + quad * 4 + r;
        if (rowg >= M) continue;
        float v = acc[i][j][r];
        if (EPI & E_BIAS) v += bias[colg];
        if (EPI & E_PE)   v += extra[(size_t)(rowg % Tdim) * N + colg];
        if (EPI & E_RES)  v += extra[(size_t)rowg * Cld + colg];
        if (EPI & E_GELU) v = 0.5f * v * (1.0f + erff(v * 0.70710678118654752f));
        size_t off = (size_t)rowg * Cld + coff + colg;
        if (EPI & E_ACC) v += C[off];
        C[off] = v;
      }
    }
  }
}

// ====== weight transpose + split: fp32 [K][N] -> bf16 hi/lo [N][K] ======
__global__ __launch_bounds__(256) void wcvt_t_split(
    const float* __restrict__ W, ushortT* __restrict__ Wh, ushortT* __restrict__ Wl,
    int K, int N)
{
  __shared__ float t[32][33];
  int k0 = blockIdx.y * 32, n0 = blockIdx.x * 32;
  int tx = threadIdx.x;   // 0..31
  int ty = threadIdx.y;   // 0..7
#pragma unroll
  for (int dy = 0; dy < 32; dy += 8)
    t[ty + dy][tx] = W[(size_t)(k0 + ty + dy) * N + n0 + tx];
  __syncthreads();
#pragma unroll
  for (int dy = 0; dy < 32; dy += 8) {
    float v = t[tx][ty + dy];
    ushortT h, l;
    split2(v, h, l);
    size_t off = (size_t)(n0 + ty + dy) * K + k0 + tx;
    Wh[off] = h; Wl[off] = l;
  }
}

// ====== flat split: fp32 -> bf16 hi/lo (conv weights, already [N][K]) ======
__global__ __launch_bounds__(256) void wcvt_split(
    const float* __restrict__ W, ushortT* __restrict__ Wh, ushortT* __restrict__ Wl, int n)
{
  int gid = blockIdx.x * 256 + threadIdx.x;
  int stride = gridDim.x * 256;
  for (int i = gid; i < n; i += stride) {
    ushortT h, l;
    split2(W[i], h, l);
    Wh[i] = h; Wl[i] = l;
  }
}

// =================== fp32 fallback GEMM (classifier only) ===================
constexpr int BM = 64, BN = 64, BK = 16, TM = 4, TN = 4;
__global__ __launch_bounds__(256) void gemm_cls(
    const float* __restrict__ A, const float* __restrict__ Bw,
    const float* __restrict__ bias, float* __restrict__ C,
    int M, int N, int K, int Ald, int Cld)
{
  __shared__ alignas(16) float As[BK][BM + 4];
  __shared__ alignas(16) float Bs[BK][BN + 4];
  int tid = threadIdx.x;
  int n0 = blockIdx.x * BN;
  int m0 = blockIdx.y * BM;
  int tx = tid & 15, ty = tid >> 4;
  float acc[TM][TN];
#pragma unroll
  for (int i = 0; i < TM; i++)
#pragma unroll
    for (int j = 0; j < TN; j++) acc[i][j] = 0.0f;
  int a_m = tid >> 2, a_k = (tid & 3) * 4;
  int b_k = tid >> 4, b_n = (tid & 15) * 4;
  for (int k0 = 0; k0 < K; k0 += BK) {
    int row = m0 + a_m;
#pragma unroll
    for (int j = 0; j < 4; j++)
      As[a_k + j][a_m] = A[(size_t)row * Ald + k0 + a_k + j];
    int kk = k0 + b_k;
#pragma unroll
    for (int j = 0; j < 4; j++) {
      int nn = n0 + b_n + j;
      Bs[b_k][b_n + j] = (nn < N) ? Bw[(size_t)kk * N + nn] : 0.0f;
    }
    __syncthreads();
#pragma unroll
    for (int k = 0; k < BK; k++) {
      float4 av = *reinterpret_cast<const float4*>(&As[k][ty * TM]);
      float4 bv = *reinterpret_cast<const float4*>(&Bs[k][tx * TN]);
      float a4[4] = {av.x, av.y, av.z, av.w};
      float b4[4] = {bv.x, bv.y, bv.z, bv.w};
#pragma unroll
      for (int i = 0; i < TM; i++)
#pragma unroll
        for (int j = 0; j < TN; j++) acc[i][j] += a4[i] * b4[j];
    }
    __syncthreads();
  }
#pragma unroll
  for (int i = 0; i < TM; i++) {
    int row = m0 + ty * TM + i;
#pragma unroll
    for (int j = 0; j < TN; j++) {
      int col = n0 + tx * TN + j;
      if (col >= N) continue;
      C[(size_t)row * Cld + col] = acc[i][j] + bias[col];
    }
  }
}

// ---- rfft over 48 tokens, real part (fp32) ----
__global__ __launch_bounds__(256) void rfft48_kernel(
    const float* __restrict__ hp, float* __restrict__ f)
{
  int kf = blockIdx.x;
  int b  = blockIdx.y;
  int tid = threadIdx.x;
  __shared__ float ct[48];
  if (tid < 48) {
    int r = (kf * tid) % 48;
    ct[tid] = cosf(6.2831853071795864f * (float)r / 48.0f);
  }
  __syncthreads();
  const float* hb = hp + (size_t)b * Tp * Hd;
  float s = 0.0f;
  for (int t = 0; t < 48; t++) s += hb[t * Hd + tid] * ct[t];
  f[((size_t)b * Ff + kf) * Hd + tid] = s;
}

// ---- attention logits + softmax; one block per (b,head); fp32 qkv ----
__global__ __launch_bounds__(128) void attn_kernel(
    const float* __restrict__ qkv, float* __restrict__ attnw)
{
  int bh = blockIdx.x;
  int b = bh >> 3, h = bh & 7;
  __shared__ float qs[Ff * DH], ks2[Ff * DH];
  __shared__ float ct[F2 * Ff], st[F2 * Ff];
  __shared__ float red[F2][DH];
  __shared__ float sm[F2];
  int tid = threadIdx.x;
  const float* base = qkv + (size_t)b * Ff * (3 * Ed) + h * DH;
  for (int e = tid; e < Ff * DH; e += 128) {
    int t = e / DH, d = e - t * DH;
    qs[e]  = base[(size_t)t * (3 * Ed) + d];
    ks2[e] = base[(size_t)t * (3 * Ed) + Ed + d];
  }
  for (int e = tid; e < F2 * Ff; e += 128) {
    int fq = e / Ff, t = e - fq * Ff;
    int r = (fq * t) % Ff;
    float ang = 6.2831853071795864f * (float)r / 25.0f;
    ct[e] = cosf(ang); st[e] = sinf(ang);
  }
  __syncthreads();
  if (tid < DH) {
    int d = tid;
    for (int fq = 0; fq < F2; fq++) {
      float qr = 0, qi = 0, kr = 0, ki = 0;
      for (int t = 0; t < Ff; t++) {
        float c = ct[fq * Ff + t], s = st[fq * Ff + t];
        float qv = qs[t * DH + d], kv = ks2[t * DH + d];
        qr += qv * c; qi += qv * s; kr += kv * c; ki += kv * s;
      }
      red[fq][d] = qr * kr + qi * ki;
    }
  }
  __syncthreads();
  if (tid < F2) {
    float s = 0;
    for (int d = 0; d < DH; d++) s += red[tid][d];
    sm[tid] = s * 0.10206207261596575f;  // 96^-0.5
  }
  __syncthreads();
  if (tid == 0) {
    float mx = sm[0];
    for (int fq = 1; fq < F2; fq++) mx = fmaxf(mx, sm[fq]);
    float den = 0;
    for (int fq = 0; fq < F2; fq++) { float e = expf(sm[fq] - mx); sm[fq] = e; den += e; }
    float inv = 1.0f / den;
    for (int fq = 0; fq < F2; fq++) sm[fq] *= inv;
  }
  __syncthreads();
  if (tid < F2) attnw[(size_t)bh * F2 + tid] = sm[tid];
}

// ---- v -> vf, scale, irfft(25); fp32 in/out ----
__global__ __launch_bounds__(128) void virfft_kernel(
    const float* __restrict__ qkv, const float* __restrict__ attnw,
    float* __restrict__ out)
{
  int bh = blockIdx.x;
  int b = bh >> 3, h = bh & 7;
  __shared__ float vs[Ff * DH];
  __shared__ float Vr[F2 * DH], Vi[F2 * DH];
  __shared__ float ct[F2 * Ff], st[F2 * Ff];
  __shared__ float af[F2];
  int tid = threadIdx.x;
  const float* vbase = qkv + (size_t)b * Ff * (3 * Ed) + 2 * Ed + h * DH;
  for (int e = tid; e < Ff * DH; e += 128) {
    int t = e / DH, d = e - t * DH;
    vs[e] = vbase[(size_t)t * (3 * Ed) + d];
  }
  for (int e = tid; e < F2 * Ff; e += 128) {
    int fq = e / Ff, t = e - fq * Ff;
    int r = (fq * t) % Ff;
    float ang = 6.2831853071795864f * (float)r / 25.0f;
    ct[e] = cosf(ang); st[e] = sinf(ang);
  }
  if (tid < F2)
    af[tid] = attnw[(size_t)bh * F2 + tid] * ((tid == 0) ? (1.0f / 25.0f) : (2.0f / 25.0f));
  __syncthreads();
  for (int e = tid; e < F2 * DH; e += 128) {
    int fq = e / DH, d = e - fq * DH;
    float vr = 0, vi = 0;
    for (int t = 0; t < Ff; t++) {
      float vv = vs[t * DH + d];
      vr += vv * ct[fq * Ff + t];
      vi -= vv * st[fq * Ff + t];
    }
    Vr[e] = vr; Vi[e] = vi;
  }
  __syncthreads();
  float* obase = out + (size_t)b * Ff * Ed + h * DH;
  for (int e = tid; e < Ff * DH; e += 128) {
    int t = e / DH, d = e - t * DH;
    float o = 0;
    for (int fq = 0; fq < F2; fq++)
      o += af[fq] * (ct[fq * Ff + t] * Vr[fq * DH + d] - st[fq * Ff + t] * Vi[fq * DH + d]);
    obase[(size_t)t * Ed + d] = o;
  }
}

// ---- layernorm over 768 (fp32 -> fp32) ----
__global__ __launch_bounds__(256) void ln_kernel(
    const float* __restrict__ x, const float* __restrict__ g,
    const float* __restrict__ bb, float* __restrict__ y)
{
  int row = blockIdx.x;
  int tid = threadIdx.x;
  const float* xr = x + (size_t)row * Ed;
  float v0 = xr[tid], v1 = xr[tid + 256], v2 = xr[tid + 512];
  __shared__ float rs[256];
  rs[tid] = v0 + v1 + v2;
  __syncthreads();
  for (int o = 128; o > 0; o >>= 1) {
    if (tid < o) rs[tid] += rs[tid + o];
    __syncthreads();
  }
  float m = rs[0] * (1.0f / 768.0f);
  __syncthreads();
  float d0 = v0 - m, d1 = v1 - m, d2 = v2 - m;
  rs[tid] = d0 * d0 + d1 * d1 + d2 * d2;
  __syncthreads();
  for (int o = 128; o > 0; o >>= 1) {
    if (tid < o) rs[tid] += rs[tid + o];
    __syncthreads();
  }
  float inv = rsqrtf(rs[0] * (1.0f / 768.0f) + 1e-5f);
  float* yr = y + (size_t)row * Ed;
  yr[tid]       = d0 * inv * g[tid]       + bb[tid];
  yr[tid + 256] = d1 * inv * g[tid + 256] + bb[tid + 256];
  yr[tid + 512] = d2 * inv * g[tid + 512] + bb[tid + 512];
}

// ---- mean over 25 tokens ----
__global__ __launch_bounds__(256) void mean_kernel(
    const float* __restrict__ x, float* __restrict__ y)
{
  int b = blockIdx.x;
  int tid = threadIdx.x;
  for (int c = tid; c < Ed; c += 256) {
    float s = 0;
    for (int t = 0; t < Ff; t++) s += x[((size_t)b * Ff + t) * Ed + c];
    y[(size_t)b * Ed + c] = s * (1.0f / 25.0f);
  }
}

extern "C" void kernel_launch(void* const* d_in, const int* in_sizes, int n_in,
                              void* d_out, int out_size, void* d_ws, size_t ws_size,
                              hipStream_t stream)
{
  const float* x       = (const float*)d_in[0];
  const float* W_in    = (const float*)d_in[1];
  const float* b_in    = (const float*)d_in[2];
  const float* pe      = (const float*)d_in[3];
  const float* W_shape = (const float*)d_in[4];
  const float* b_shape = (const float*)d_in[5];
  const float* W_patch = (const float*)d_in[6];
  const float* b_patch = (const float*)d_in[7];
  const float* conv_w1 = (const float*)d_in[8];
  const float* conv_b1 = (const float*)d_in[9];
  const float* conv_w2 = (const float*)d_in[10];
  const float* conv_b2 = (const float*)d_in[11];
  const float* conv_w4 = (const float*)d_in[12];
  const float* conv_b4 = (const float*)d_in[13];
  const float* ln1_g   = (const float*)d_in[14];
  const float* ln1_b   = (const float*)d_in[15];
  const float* Wqkv    = (const float*)d_in[16];
  const float* Wo      = (const float*)d_in[17];
  const float* bo      = (const float*)d_in[18];
  const float* ln2_g   = (const float*)d_in[19];
  const float* ln2_b   = (const float*)d_in[20];
  const float* Wf1     = (const float*)d_in[21];
  const float* bf1     = (const float*)d_in[22];
  const float* Wf2     = (const float*)d_in[23];
  const float* bf2     = (const float*)d_in[24];
  const float* ssm_w   = (const float*)d_in[25];
  const float* ssm_b   = (const float*)d_in[26];
  const float* ssm_g   = (const float*)d_in[27];
  const float* ssm_bn  = (const float*)d_in[28];
  const float* W_out   = (const float*)d_in[29];
  const float* b_out   = (const float*)d_in[30];
  float* out = (float*)d_out;

  // ---- workspace (floats): A0 9.83M | A1 9.83M | A2 6.4M | Wb 4.72M = 123 MB ----
  float* A0 = (float*)d_ws;
  float* A1 = A0 + 9830400;
  float* A2 = A1 + 9830400;
  ushortT* Wb = (ushortT*)(A2 + 6400000);   // 9,437,184 bf16 slots
  float* attnw_ws = A2 + 6300000;           // 6,656 floats used

  dim3 blk(256);
  dim3 wblk(32, 8);
  const int Mf = Bsz * Ff;   // 12800

  // ---------------- phase-0 weights: split hi/lo ----------------
  // offsets in bf16 elements
  ushortT* WinH = Wb + 0;        ushortT* WinL = Wb + 16384;
  ushortT* WshH = Wb + 32768;    ushortT* WshL = Wb + 98304;
  ushortT* WpaH = Wb + 163840;   ushortT* WpaL = Wb + 294912;
  ushortT* c1H  = Wb + 425984;   ushortT* c1L  = Wb + 491520;
  ushortT* c2H  = Wb + 557056;   ushortT* c2L  = Wb + 688128;
  ushortT* c4H  = Wb + 819200;   ushortT* c4L  = Wb + 1081344;
  wcvt_t_split<<<dim3(Hd / 32, DIN / 32), wblk, 0, stream>>>(W_in, WinH, WinL, DIN, Hd);
  wcvt_t_split<<<dim3(Hd / 32, Hd / 32), wblk, 0, stream>>>(W_shape, WshH, WshL, Hd, Hd);
  wcvt_t_split<<<dim3(Hd / 32, (Pp * Hd) / 32), wblk, 0, stream>>>(W_patch, WpaH, WpaL, Pp * Hd, Hd);
  wcvt_split<<<64, blk, 0, stream>>>(conv_w1, c1H, c1L, Hd * Hd);
  wcvt_split<<<64, blk, 0, stream>>>(conv_w2, c2H, c2L, Hd * Hd * 2);
  wcvt_split<<<128, blk, 0, stream>>>(conv_w4, c4H, c4L, Hd * Hd * 4);

  // ---------------- phase 0: 2 chunks of 256 batches ----------------
  for (int c = 0; c < 2; c++) {
    const int NB = 256;
    const int M96 = NB * Tin;      // 24576
    const int Mpch = NB * Tp;      // 12288
    const int Mfch = NB * Ff;      // 6400
    const float* xc = x + (size_t)c * NB * Tin * DIN;

    gemm3<0, E_BIAS | E_PE, 0><<<dim3(Hd / GBN, M96 / GBM), blk, 0, stream>>>(
        xc, WinH, WinL, b_in, pe, A0, M96, Hd, DIN, DIN, Tin, 0, Hd, 0);
    gemm3<1, E_BIAS | E_RES, 0><<<dim3(Hd / GBN, M96 / GBM), blk, 0, stream>>>(
        A0, WshH, WshL, b_shape, A0, A2, M96, Hd, Hd, Hd, Tin, 0, Hd, 0);
    gemm3<0, E_BIAS, 0><<<dim3(Hd / GBN, Mpch / GBM), blk, 0, stream>>>(
        A2, WpaH, WpaL, b_patch, nullptr, A0, Mpch, Hd, Pp * Hd, Pp * Hd, 0, 0, Hd, 0);
    rfft48_kernel<<<dim3(Ff, NB), blk, 0, stream>>>(A0, A2);
    float* hrows = A1 + (size_t)c * Mfch * Ed;
    gemm3<0, E_BIAS, 0><<<dim3(Hd / GBN, Mfch / GBM), blk, 0, stream>>>(
        A2, c1H, c1L, conv_b1, nullptr, hrows, Mfch, Hd, Hd, Hd, Ff, 0, Ed, 0);
    gemm3<2, E_BIAS, 2><<<dim3(Hd / GBN, Mfch / GBM), blk, 0, stream>>>(
        A2, c2H, c2L, conv_b2, nullptr, hrows, Mfch, Hd, Hd * 2, Hd, Ff, 0, Ed, Hd);
    gemm3<2, E_BIAS, 4><<<dim3(Hd / GBN, Mfch / GBM), blk, 0, stream>>>(
        A2, c4H, c4L, conv_b4, nullptr, hrows, Mfch, Hd, Hd * 4, Hd, Ff, 1, Ed, 2 * Hd);
  }

  // ---------------- transformer layers ----------------
  // weight arena (bf16 offsets)
  ushortT* qkH = Wb + 0;        ushortT* qkL = Wb + 1769472;   // [2304][768]
  ushortT* woH = Wb + 3538944;  ushortT* woL = Wb + 4128768;   // [768][768]
  ushortT* f1H = Wb + 0;        ushortT* f1L = Wb + 2359296;   // [3072][768]
  ushortT* f2H = Wb + 4718592;  ushortT* f2L = Wb + 7077888;   // [768][3072]

  const int NBA = 64;            // attention chunk batches (8 chunks)
  const int Mca = NBA * Ff;      // 1600 rows

  for (int l = 0; l < Ll; l++) {
    const float* Wqkv_l = Wqkv + (size_t)l * Ed * (3 * Ed);
    const float* Wo_l   = Wo   + (size_t)l * Ed * Ed;
    const float* bo_l   = bo   + (size_t)l * Ed;
    const float* Wf1_l  = Wf1  + (size_t)l * Ed * (4 * Ed);
    const float* bf1_l  = bf1  + (size_t)l * (4 * Ed);
    const float* Wf2_l  = Wf2  + (size_t)l * (4 * Ed) * Ed;
    const float* bf2_l  = bf2  + (size_t)l * Ed;

    wcvt_t_split<<<dim3((3 * Ed) / 32, Ed / 32), wblk, 0, stream>>>(Wqkv_l, qkH, qkL, Ed, 3 * Ed);
    wcvt_t_split<<<dim3(Ed / 32, Ed / 32), wblk, 0, stream>>>(Wo_l, woH, woL, Ed, Ed);

    ln_kernel<<<Mf, blk, 0, stream>>>(A1, ln1_g + (size_t)l * Ed, ln1_b + (size_t)l * Ed, A0);

    for (int c = 0; c < 8; c++) {
      float* arows = A0 + (size_t)c * Mca * Ed;
      gemm3<0, 0, 0><<<dim3((3 * Ed) / GBN, (Mca + GBM - 1) / GBM), blk, 0, stream>>>(
          arows, qkH, qkL, nullptr, nullptr, A2, Mca, 3 * Ed, Ed, Ed, 0, 0, 3 * Ed, 0);
      attn_kernel<<<NBA * NHEAD, dim3(128), 0, stream>>>(A2, attnw_ws);
      virfft_kernel<<<NBA * NHEAD, dim3(128), 0, stream>>>(A2, attnw_ws, arows);
    }
    gemm3<0, E_BIAS | E_ACC, 0><<<dim3(Ed / GBN, Mf / GBM), blk, 0, stream>>>(
        A0, woH, woL, bo_l, nullptr, A1, Mf, Ed, Ed, Ed, 0, 0, Ed, 0);

    wcvt_t_split<<<dim3((4 * Ed) / 32, Ed / 32), wblk, 0, stream>>>(Wf1_l, f1H, f1L, Ed, 4 * Ed);
    wcvt_t_split<<<dim3(Ed / 32, (4 * Ed) / 32), wblk, 0, stream>>>(Wf2_l, f2H, f2L, 4 * Ed, Ed);

    ln_kernel<<<Mf, blk, 0, stream>>>(A1, ln2_g + (size_t)l * Ed, ln2_b + (size_t)l * Ed, A0);

    for (int row0 = 0; row0 < Mf; row0 += 2048) {
      int rows = (Mf - row0 < 2048) ? (Mf - row0) : 2048;
      gemm3<0, E_BIAS | E_GELU, 0><<<dim3((4 * Ed) / GBN, rows / GBM), blk, 0, stream>>>(
          A0 + (size_t)row0 * Ed, f1H, f1L, bf1_l, nullptr, A2, rows, 4 * Ed, Ed, Ed, 0, 0, 4 * Ed, 0);
      gemm3<0, E_BIAS | E_ACC, 0><<<dim3(Ed / GBN, rows / GBM), blk, 0, stream>>>(
          A2, f2H, f2L, bf2_l, nullptr, A1 + (size_t)row0 * Ed, rows, Ed, 4 * Ed, 4 * Ed, 0, 0, Ed, 0);
    }
  }

  // ---------------- tail ----------------
  ushortT* ssH = Wb + 0; ushortT* ssL = Wb + 1769472;
  wcvt_split<<<512, blk, 0, stream>>>(ssm_w, ssH, ssL, Ed * Ed * 3);
  gemm3<2, E_BIAS | E_RES, 3><<<dim3(Ed / GBN, Mf / GBM), blk, 0, stream>>>(
      A1, ssH, ssL, ssm_b, A1, A0, Mf, Ed, Ed * 3, Ed, Ff, 1, Ed, 0);

  ln_kernel<<<Mf, blk, 0, stream>>>(A0, ssm_g, ssm_bn, A1);
  mean_kernel<<<Bsz, blk, 0, stream>>>(A1, A2);
  gemm_cls<<<dim3(2, Bsz / BM), blk, 0, stream>>>(
      A2, W_out, b_out, out, Bsz, NCls, Ed, Ed, NCls);
}

// Round 5
// 9184.369 us; speedup vs baseline: 1.8434x; 1.1132x over previous
//
#include <hip/hip_runtime.h>
#include <hip/hip_bf16.h>
#include <math.h>

// ---------------- problem constants ----------------
#define Bsz 512
#define Tin 96
#define DIN 64
#define Hd  256
#define Pp  2
#define Ll  4
#define NHEAD 8
#define Ed  768          // 3*H
#define NCls 100
#define Tp  48           // T/P tokens after patch
#define Ff  25           // rfft freqs of 48
#define F2  13           // rfft freqs of 25
#define DH  96           // E / HEADS

// epilogue flags
#define E_BIAS 1
#define E_PE   2
#define E_RES  4
#define E_ACC  8
#define E_GELU 16
#define E_OUTS 32        // write split hi/lo bf16 planes

typedef unsigned short ushortT;
typedef unsigned short ushort8 __attribute__((ext_vector_type(8)));
typedef short short8 __attribute__((ext_vector_type(8)));
typedef float f32x4 __attribute__((ext_vector_type(4)));

static __device__ __forceinline__ ushortT f2bf(float f) {
  __hip_bfloat16 h = __float2bfloat16(f);
  return *reinterpret_cast<ushortT*>(&h);
}
static __device__ __forceinline__ float bfbits2f(ushortT u) {
  unsigned int x = ((unsigned int)u) << 16;
  return __uint_as_float(x);
}
static __device__ __forceinline__ void split2(float v, ushortT& h, ushortT& l) {
  h = f2bf(v);
  l = f2bf(v - bfbits2f(h));
}

// =================== bf16x3 split MFMA GEMM ===================
// AMODE: 0 plain fp32/split A; 1 diff along Tdim; 2 tap-major conv (K=(tap,i), Kin inner)
// ASRC:  0 A fp32 [M,K] (split at stage time); 1 A pre-split planes Ah/Al [M,K] bf16
// B: pre-split bf16 hi/lo [N][K] row-major.
// C: fp32 (default), or split planes Coh/Col when E_OUTS.
constexpr int GBM = 128, GBN = 128, GBK = 32, LDK = GBK + 8;

template<int AMODE, int ASRC, int EPI>
__global__ __launch_bounds__(256) void gemm3(
    const float* __restrict__ A,
    const ushortT* __restrict__ Ah, const ushortT* __restrict__ Al,
    const ushortT* __restrict__ Bh, const ushortT* __restrict__ Bl,
    const float* __restrict__ bias, const float* __restrict__ extra,
    float* __restrict__ C, ushortT* __restrict__ Coh, ushortT* __restrict__ Col,
    int M, int N, int K, int Ald, int Tdim, int lo, int Kin, int Cld, int coff)
{
  __shared__ ushortT Ash[GBM * LDK];
  __shared__ ushortT Asl[GBM * LDK];
  __shared__ ushortT Bsh[GBN * LDK];
  __shared__ ushortT Bsl[GBN * LDK];
  int tid = threadIdx.x;
  int m0 = blockIdx.y * GBM, n0 = blockIdx.x * GBN;
  int wid = tid >> 6, lane = tid & 63;
  int wm = wid & 1, wn = wid >> 1;
  int m16 = lane & 15, quad = lane >> 4;

  f32x4 acc[4][4] = {};

  int srow = tid >> 1;           // 0..127
  int skh  = (tid & 1) * 16;     // 0 or 16

  for (int k0 = 0; k0 < K; k0 += GBK) {
    // ---- stage A ----
    {
      int row = m0 + srow;
      if (row >= M) row = M - 1;           // clamp (epilogue guards writes)
      if (ASRC == 1) {
        size_t aoff = (size_t)row * Ald + k0 + skh;
        *(uint4*)&Ash[srow * LDK + skh]     = *(const uint4*)(Ah + aoff);
        *(uint4*)&Ash[srow * LDK + skh + 8] = *(const uint4*)(Ah + aoff + 8);
        *(uint4*)&Asl[srow * LDK + skh]     = *(const uint4*)(Al + aoff);
        *(uint4*)&Asl[srow * LDK + skh + 8] = *(const uint4*)(Al + aoff + 8);
      } else {
        float tf[16];
        if (AMODE == 0) {
          const float* p = A + (size_t)row * Ald + k0 + skh;
#pragma unroll
          for (int j = 0; j < 16; j += 4) {
            float4 v = *(const float4*)(p + j);
            tf[j] = v.x; tf[j+1] = v.y; tf[j+2] = v.z; tf[j+3] = v.w;
          }
        } else if (AMODE == 1) {
          int t = row % Tdim;
          const float* p = A + (size_t)row * Ald + k0 + skh;
#pragma unroll
          for (int j = 0; j < 16; j += 4) {
            float4 v = *(const float4*)(p + j);
            float4 w = (t != 0) ? *(const float4*)(p - Ald + j) : v;
            tf[j] = v.x - w.x; tf[j+1] = v.y - w.y;
            tf[j+2] = v.z - w.z; tf[j+3] = v.w - w.w;
          }
        } else {   // AMODE == 2: tap-major conv; tap uniform over this 16-seg
          int kk = k0 + skh;
          int tap = kk / Kin;
          int i0  = kk - tap * Kin;
          int bb = row / Tdim;
          int t  = row - bb * Tdim;
          int tt = t - lo + tap;
          if (tt >= 0 && tt < Tdim) {
            const float* p = A + ((size_t)bb * Tdim + tt) * Ald + i0;
#pragma unroll
            for (int j = 0; j < 16; j += 4) {
              float4 v = *(const float4*)(p + j);
              tf[j] = v.x; tf[j+1] = v.y; tf[j+2] = v.z; tf[j+3] = v.w;
            }
          } else {
#pragma unroll
            for (int j = 0; j < 16; j++) tf[j] = 0.0f;
          }
        }
        ushortT th[16], tl[16];
#pragma unroll
        for (int j = 0; j < 16; j++) split2(tf[j], th[j], tl[j]);
        *(ushort8*)&Ash[srow * LDK + skh]     = *(ushort8*)&th[0];
        *(ushort8*)&Ash[srow * LDK + skh + 8] = *(ushort8*)&th[8];
        *(ushort8*)&Asl[srow * LDK + skh]     = *(ushort8*)&tl[0];
        *(ushort8*)&Asl[srow * LDK + skh + 8] = *(ushort8*)&tl[8];
      }
    }
    // ---- stage B hi/lo ----
    {
      size_t boff = (size_t)(n0 + srow) * K + k0 + skh;
      *(uint4*)&Bsh[srow * LDK + skh]     = *(const uint4*)(Bh + boff);
      *(uint4*)&Bsh[srow * LDK + skh + 8] = *(const uint4*)(Bh + boff + 8);
      *(uint4*)&Bsl[srow * LDK + skh]     = *(const uint4*)(Bl + boff);
      *(uint4*)&Bsl[srow * LDK + skh + 8] = *(const uint4*)(Bl + boff + 8);
    }
    __syncthreads();
    short8 ah[4], al[4], bh[4], bl[4];
#pragma unroll
    for (int i = 0; i < 4; i++) {
      int ro = (wm * 64 + i * 16 + m16) * LDK + quad * 8;
      ah[i] = *(short8*)&Ash[ro];
      al[i] = *(short8*)&Asl[ro];
    }
#pragma unroll
    for (int j = 0; j < 4; j++) {
      int ro = (wn * 64 + j * 16 + m16) * LDK + quad * 8;
      bh[j] = *(short8*)&Bsh[ro];
      bl[j] = *(short8*)&Bsl[ro];
    }
#pragma unroll
    for (int i = 0; i < 4; i++)
#pragma unroll
      for (int j = 0; j < 4; j++) {
        acc[i][j] = __builtin_amdgcn_mfma_f32_16x16x32_bf16(ah[i], bh[j], acc[i][j], 0, 0, 0);
        acc[i][j] = __builtin_amdgcn_mfma_f32_16x16x32_bf16(al[i], bh[j], acc[i][j], 0, 0, 0);
        acc[i][j] = __builtin_amdgcn_mfma_f32_16x16x32_bf16(ah[i], bl[j], acc[i][j], 0, 0, 0);
      }
    __syncthreads();
  }

  // ---- epilogue: C/D map col=lane&15, row=quad*4+r ----
#pragma unroll
  for (int i = 0; i < 4; i++) {
#pragma unroll
    for (int j = 0; j < 4; j++) {
      int colg = n0 + wn * 64 + j * 16 + m16;
#pragma unroll
      for (int r = 0; r < 4; r++) {
        int rowg = m0 + wm * 64 + i * 16 + quad * 4 + r;
        if (rowg >= M) continue;
        float v = acc[i][j][r];
        if (EPI & E_BIAS) v += bias[colg];
        if (EPI & E_PE)   v += extra[(size_t)(rowg % Tdim) * N + colg];
        if (EPI & E_RES)  v += extra[(size_t)rowg * Cld + colg];
        if (EPI & E_GELU) v = 0.5f * v * (1.0f + erff(v * 0.70710678118654752f));
        size_t off = (size_t)rowg * Cld + coff + colg;
        if (EPI & E_OUTS) {
          ushortT h, l; split2(v, h, l);
          Coh[off] = h; Col[off] = l;
        } else {
          if (EPI & E_ACC) v += C[off];
          C[off] = v;
        }
      }
    }
  }
}

// ====== weight transpose + split: fp32 [K][N] -> bf16 hi/lo [N][K] ======
__global__ __launch_bounds__(256) void wcvt_t_split(
    const float* __restrict__ W, ushortT* __restrict__ Wh, ushortT* __restrict__ Wl,
    int K, int N)
{
  __shared__ float t[32][33];
  int k0 = blockIdx.y * 32, n0 = blockIdx.x * 32;
  int tx = threadIdx.x;   // 0..31
  int ty = threadIdx.y;   // 0..7
#pragma unroll
  for (int dy = 0; dy < 32; dy += 8)
    t[ty + dy][tx] = W[(size_t)(k0 + ty + dy) * N + n0 + tx];
  __syncthreads();
#pragma unroll
  for (int dy = 0; dy < 32; dy += 8) {
    float v = t[tx][ty + dy];
    ushortT h, l;
    split2(v, h, l);
    size_t off = (size_t)(n0 + ty + dy) * K + k0 + tx;
    Wh[off] = h; Wl[off] = l;
  }
}

// ====== flat split: fp32 -> bf16 hi/lo ======
__global__ __launch_bounds__(256) void wcvt_split(
    const float* __restrict__ W, ushortT* __restrict__ Wh, ushortT* __restrict__ Wl, int n)
{
  int gid = blockIdx.x * 256 + threadIdx.x;
  int stride = gridDim.x * 256;
  for (int i = gid; i < n; i += stride) {
    ushortT h, l;
    split2(W[i], h, l);
    Wh[i] = h; Wl[i] = l;
  }
}

// ====== conv weight split, tap-major: [O][Kin][NT] -> [O][NT*Kin] (tap outer) ======
__global__ __launch_bounds__(256) void wcvt_split_tm(
    const float* __restrict__ W, ushortT* __restrict__ Wh, ushortT* __restrict__ Wl,
    int O, int Kin, int NT)
{
  int n = O * Kin * NT;
  int gid = blockIdx.x * 256 + threadIdx.x;
  int stride = gridDim.x * 256;
  for (int idx = gid; idx < n; idx += stride) {
    int o = idx / (Kin * NT);
    int r = idx - o * (Kin * NT);
    int tap = r / Kin;
    int i = r - tap * Kin;
    float v = W[(size_t)o * Kin * NT + (size_t)i * NT + tap];
    ushortT h, l;
    split2(v, h, l);
    Wh[idx] = h; Wl[idx] = l;
  }
}

// =================== fp32 fallback GEMM (classifier only) ===================
constexpr int BM = 64, BN = 64, BK = 16, TM = 4, TN = 4;
__global__ __launch_bounds__(256) void gemm_cls(
    const float* __restrict__ A, const float* __restrict__ Bw,
    const float* __restrict__ bias, float* __restrict__ C,
    int M, int N, int K, int Ald, int Cld)
{
  __shared__ alignas(16) float As[BK][BM + 4];
  __shared__ alignas(16) float Bs[BK][BN + 4];
  int tid = threadIdx.x;
  int n0 = blockIdx.x * BN;
  int m0 = blockIdx.y * BM;
  int tx = tid & 15, ty = tid >> 4;
  float acc[TM][TN];
#pragma unroll
  for (int i = 0; i < TM; i++)
#pragma unroll
    for (int j = 0; j < TN; j++) acc[i][j] = 0.0f;
  int a_m = tid >> 2, a_k = (tid & 3) * 4;
  int b_k = tid >> 4, b_n = (tid & 15) * 4;
  for (int k0 = 0; k0 < K; k0 += BK) {
    int row = m0 + a_m;
#pragma unroll
    for (int j = 0; j < 4; j++)
      As[a_k + j][a_m] = A[(size_t)row * Ald + k0 + a_k + j];
    int kk = k0 + b_k;
#pragma unroll
    for (int j = 0; j < 4; j++) {
      int nn = n0 + b_n + j;
      Bs[b_k][b_n + j] = (nn < N) ? Bw[(size_t)kk * N + nn] : 0.0f;
    }
    __syncthreads();
#pragma unroll
    for (int k = 0; k < BK; k++) {
      float4 av = *reinterpret_cast<const float4*>(&As[k][ty * TM]);
      float4 bv = *reinterpret_cast<const float4*>(&Bs[k][tx * TN]);
      float a4[4] = {av.x, av.y, av.z, av.w};
      float b4[4] = {bv.x, bv.y, bv.z, bv.w};
#pragma unroll
      for (int i = 0; i < TM; i++)
#pragma unroll
        for (int j = 0; j < TN; j++) acc[i][j] += a4[i] * b4[j];
    }
    __syncthreads();
  }
#pragma unroll
  for (int i = 0; i < TM; i++) {
    int row = m0 + ty * TM + i;
#pragma unroll
    for (int j = 0; j < TN; j++) {
      int col = n0 + tx * TN + j;
      if (col >= N) continue;
      C[(size_t)row * Cld + col] = acc[i][j] + bias[col];
    }
  }
}

// ---- rfft over 48 tokens, real part (fp32) ----
__global__ __launch_bounds__(256) void rfft48_kernel(
    const float* __restrict__ hp, float* __restrict__ f)
{
  int kf = blockIdx.x;
  int b  = blockIdx.y;
  int tid = threadIdx.x;
  __shared__ float ct[48];
  if (tid < 48) {
    int r = (kf * tid) % 48;
    ct[tid] = cosf(6.2831853071795864f * (float)r / 48.0f);
  }
  __syncthreads();
  const float* hb = hp + (size_t)b * Tp * Hd;
  float s = 0.0f;
  for (int t = 0; t < 48; t++) s += hb[t * Hd + tid] * ct[t];
  f[((size_t)b * Ff + kf) * Hd + tid] = s;
}

// ---- attention logits + softmax; one block per (b,head); fp32 qkv ----
__global__ __launch_bounds__(128) void attn_kernel(
    const float* __restrict__ qkv, float* __restrict__ attnw)
{
  int bh = blockIdx.x;
  int b = bh >> 3, h = bh & 7;
  __shared__ float qs[Ff * DH], ks2[Ff * DH];
  __shared__ float ct[F2 * Ff], st[F2 * Ff];
  __shared__ float red[F2][DH];
  __shared__ float sm[F2];
  int tid = threadIdx.x;
  const float* base = qkv + (size_t)b * Ff * (3 * Ed) + h * DH;
  for (int e = tid; e < Ff * DH; e += 128) {
    int t = e / DH, d = e - t * DH;
    qs[e]  = base[(size_t)t * (3 * Ed) + d];
    ks2[e] = base[(size_t)t * (3 * Ed) + Ed + d];
  }
  for (int e = tid; e < F2 * Ff; e += 128) {
    int fq = e / Ff, t = e - fq * Ff;
    int r = (fq * t) % Ff;
    float ang = 6.2831853071795864f * (float)r / 25.0f;
    ct[e] = cosf(ang); st[e] = sinf(ang);
  }
  __syncthreads();
  if (tid < DH) {
    int d = tid;
    for (int fq = 0; fq < F2; fq++) {
      float qr = 0, qi = 0, kr = 0, ki = 0;
      for (int t = 0; t < Ff; t++) {
        float c = ct[fq * Ff + t], s = st[fq * Ff + t];
        float qv = qs[t * DH + d], kv = ks2[t * DH + d];
        qr += qv * c; qi += qv * s; kr += kv * c; ki += kv * s;
      }
      red[fq][d] = qr * kr + qi * ki;
    }
  }
  __syncthreads();
  if (tid < F2) {
    float s = 0;
    for (int d = 0; d < DH; d++) s += red[tid][d];
    sm[tid] = s * 0.10206207261596575f;  // 96^-0.5
  }
  __syncthreads();
  if (tid == 0) {
    float mx = sm[0];
    for (int fq = 1; fq < F2; fq++) mx = fmaxf(mx, sm[fq]);
    float den = 0;
    for (int fq = 0; fq < F2; fq++) { float e = expf(sm[fq] - mx); sm[fq] = e; den += e; }
    float inv = 1.0f / den;
    for (int fq = 0; fq < F2; fq++) sm[fq] *= inv;
  }
  __syncthreads();
  if (tid < F2) attnw[(size_t)bh * F2 + tid] = sm[tid];
}

// ---- v -> vf, scale, irfft(25); fp32 in, split bf16 out ----
__global__ __launch_bounds__(128) void virfft_kernel(
    const float* __restrict__ qkv, const float* __restrict__ attnw,
    ushortT* __restrict__ oh, ushortT* __restrict__ ol)
{
  int bh = blockIdx.x;
  int b = bh >> 3, h = bh & 7;
  __shared__ float vs[Ff * DH];
  __shared__ float Vr[F2 * DH], Vi[F2 * DH];
  __shared__ float ct[F2 * Ff], st[F2 * Ff];
  __shared__ float af[F2];
  int tid = threadIdx.x;
  const float* vbase = qkv + (size_t)b * Ff * (3 * Ed) + 2 * Ed + h * DH;
  for (int e = tid; e < Ff * DH; e += 128) {
    int t = e / DH, d = e - t * DH;
    vs[e] = vbase[(size_t)t * (3 * Ed) + d];
  }
  for (int e = tid; e < F2 * Ff; e += 128) {
    int fq = e / Ff, t = e - fq * Ff;
    int r = (fq * t) % Ff;
    float ang = 6.2831853071795864f * (float)r / 25.0f;
    ct[e] = cosf(ang); st[e] = sinf(ang);
  }
  if (tid < F2)
    af[tid] = attnw[(size_t)bh * F2 + tid] * ((tid == 0) ? (1.0f / 25.0f) : (2.0f / 25.0f));
  __syncthreads();
  for (int e = tid; e < F2 * DH; e += 128) {
    int fq = e / DH, d = e - fq * DH;
    float vr = 0, vi = 0;
    for (int t = 0; t < Ff; t++) {
      float vv = vs[t * DH + d];
      vr += vv * ct[fq * Ff + t];
      vi -= vv * st[fq * Ff + t];
    }
    Vr[e] = vr; Vi[e] = vi;
  }
  __syncthreads();
  size_t ob = (size_t)b * Ff * Ed + h * DH;
  for (int e = tid; e < Ff * DH; e += 128) {
    int t = e / DH, d = e - t * DH;
    float o = 0;
    for (int fq = 0; fq < F2; fq++)
      o += af[fq] * (ct[fq * Ff + t] * Vr[fq * DH + d] - st[fq * Ff + t] * Vi[fq * DH + d]);
    ushortT hh, ll;
    split2(o, hh, ll);
    oh[ob + (size_t)t * Ed + d] = hh;
    ol[ob + (size_t)t * Ed + d] = ll;
  }
}

// ---- layernorm over 768, split bf16 out ----
__global__ __launch_bounds__(256) void ln_split(
    const float* __restrict__ x, const float* __restrict__ g,
    const float* __restrict__ bb, ushortT* __restrict__ yh, ushortT* __restrict__ yl)
{
  int row = blockIdx.x;
  int tid = threadIdx.x;
  const float* xr = x + (size_t)row * Ed;
  float v0 = xr[tid], v1 = xr[tid + 256], v2 = xr[tid + 512];
  __shared__ float rs[256];
  rs[tid] = v0 + v1 + v2;
  __syncthreads();
  for (int o = 128; o > 0; o >>= 1) {
    if (tid < o) rs[tid] += rs[tid + o];
    __syncthreads();
  }
  float m = rs[0] * (1.0f / 768.0f);
  __syncthreads();
  float d0 = v0 - m, d1 = v1 - m, d2 = v2 - m;
  rs[tid] = d0 * d0 + d1 * d1 + d2 * d2;
  __syncthreads();
  for (int o = 128; o > 0; o >>= 1) {
    if (tid < o) rs[tid] += rs[tid + o];
    __syncthreads();
  }
  float inv = rsqrtf(rs[0] * (1.0f / 768.0f) + 1e-5f);
  size_t base = (size_t)row * Ed;
  float o0 = d0 * inv * g[tid] + bb[tid];
  float o1 = d1 * inv * g[tid + 256] + bb[tid + 256];
  float o2 = d2 * inv * g[tid + 512] + bb[tid + 512];
  ushortT h, l;
  split2(o0, h, l); yh[base + tid] = h;       yl[base + tid] = l;
  split2(o1, h, l); yh[base + tid + 256] = h; yl[base + tid + 256] = l;
  split2(o2, h, l); yh[base + tid + 512] = h; yl[base + tid + 512] = l;
}

// ---- layernorm over 768, fp32 out (final) ----
__global__ __launch_bounds__(256) void ln_f32(
    const float* __restrict__ x, const float* __restrict__ g,
    const float* __restrict__ bb, float* __restrict__ y)
{
  int row = blockIdx.x;
  int tid = threadIdx.x;
  const float* xr = x + (size_t)row * Ed;
  float v0 = xr[tid], v1 = xr[tid + 256], v2 = xr[tid + 512];
  __shared__ float rs[256];
  rs[tid] = v0 + v1 + v2;
  __syncthreads();
  for (int o = 128; o > 0; o >>= 1) {
    if (tid < o) rs[tid] += rs[tid + o];
    __syncthreads();
  }
  float m = rs[0] * (1.0f / 768.0f);
  __syncthreads();
  float d0 = v0 - m, d1 = v1 - m, d2 = v2 - m;
  rs[tid] = d0 * d0 + d1 * d1 + d2 * d2;
  __syncthreads();
  for (int o = 128; o > 0; o >>= 1) {
    if (tid < o) rs[tid] += rs[tid + o];
    __syncthreads();
  }
  float inv = rsqrtf(rs[0] * (1.0f / 768.0f) + 1e-5f);
  float* yr = y + (size_t)row * Ed;
  yr[tid]       = d0 * inv * g[tid]       + bb[tid];
  yr[tid + 256] = d1 * inv * g[tid + 256] + bb[tid + 256];
  yr[tid + 512] = d2 * inv * g[tid + 512] + bb[tid + 512];
}

// ---- mean over 25 tokens ----
__global__ __launch_bounds__(256) void mean_kernel(
    const float* __restrict__ x, float* __restrict__ y)
{
  int b = blockIdx.x;
  int tid = threadIdx.x;
  for (int c = tid; c < Ed; c += 256) {
    float s = 0;
    for (int t = 0; t < Ff; t++) s += x[((size_t)b * Ff + t) * Ed + c];
    y[(size_t)b * Ed + c] = s * (1.0f / 25.0f);
  }
}

extern "C" void kernel_launch(void* const* d_in, const int* in_sizes, int n_in,
                              void* d_out, int out_size, void* d_ws, size_t ws_size,
                              hipStream_t stream)
{
  const float* x       = (const float*)d_in[0];
  const float* W_in    = (const float*)d_in[1];
  const float* b_in    = (const float*)d_in[2];
  const float* pe      = (const float*)d_in[3];
  const float* W_shape = (const float*)d_in[4];
  const float* b_shape = (const float*)d_in[5];
  const float* W_patch = (const float*)d_in[6];
  const float* b_patch = (const float*)d_in[7];
  const float* conv_w1 = (const float*)d_in[8];
  const float* conv_b1 = (const float*)d_in[9];
  const float* conv_w2 = (const float*)d_in[10];
  const float* conv_b2 = (const float*)d_in[11];
  const float* conv_w4 = (const float*)d_in[12];
  const float* conv_b4 = (const float*)d_in[13];
  const float* ln1_g   = (const float*)d_in[14];
  const float* ln1_b   = (const float*)d_in[15];
  const float* Wqkv    = (const float*)d_in[16];
  const float* Wo      = (const float*)d_in[17];
  const float* bo      = (const float*)d_in[18];
  const float* ln2_g   = (const float*)d_in[19];
  const float* ln2_b   = (const float*)d_in[20];
  const float* Wf1     = (const float*)d_in[21];
  const float* bf1     = (const float*)d_in[22];
  const float* Wf2     = (const float*)d_in[23];
  const float* bf2     = (const float*)d_in[24];
  const float* ssm_w   = (const float*)d_in[25];
  const float* ssm_b   = (const float*)d_in[26];
  const float* ssm_g   = (const float*)d_in[27];
  const float* ssm_bn  = (const float*)d_in[28];
  const float* W_out   = (const float*)d_in[29];
  const float* b_out   = (const float*)d_in[30];
  float* out = (float*)d_out;

  // ---- workspace (floats): A0 9.83M | A1 9.83M | A2 6.4M | Wb 4.72M = 123 MB ----
  float* A0 = (float*)d_ws;
  float* A1 = A0 + 9830400;
  float* A2 = A1 + 9830400;
  ushortT* Wb = (ushortT*)(A2 + 6400000);   // 9,437,184 bf16 slots
  float* attnw_ws = A2 + 6300000;           // 6,656 floats used
  // split activation planes over A0 (12800x768 each)
  ushortT* Ahp = (ushortT*)A0;
  ushortT* Alp = Ahp + 9830400;

  dim3 blk(256);
  dim3 wblk(32, 8);
  const int Mf = Bsz * Ff;   // 12800
  const ushortT* NUS = nullptr;
  const float* NF = nullptr;

  // ---------------- phase-0 weights: split hi/lo ----------------
  ushortT* WinH = Wb + 0;        ushortT* WinL = Wb + 16384;
  ushortT* WshH = Wb + 32768;    ushortT* WshL = Wb + 98304;
  ushortT* WpaH = Wb + 163840;   ushortT* WpaL = Wb + 294912;
  ushortT* c1H  = Wb + 425984;   ushortT* c1L  = Wb + 491520;
  ushortT* c2H  = Wb + 557056;   ushortT* c2L  = Wb + 688128;
  ushortT* c4H  = Wb + 819200;   ushortT* c4L  = Wb + 1081344;
  wcvt_t_split<<<dim3(Hd / 32, DIN / 32), wblk, 0, stream>>>(W_in, WinH, WinL, DIN, Hd);
  wcvt_t_split<<<dim3(Hd / 32, Hd / 32), wblk, 0, stream>>>(W_shape, WshH, WshL, Hd, Hd);
  wcvt_t_split<<<dim3(Hd / 32, (Pp * Hd) / 32), wblk, 0, stream>>>(W_patch, WpaH, WpaL, Pp * Hd, Hd);
  wcvt_split<<<64, blk, 0, stream>>>(conv_w1, c1H, c1L, Hd * Hd);
  wcvt_split_tm<<<128, blk, 0, stream>>>(conv_w2, c2H, c2L, Hd, Hd, 2);
  wcvt_split_tm<<<256, blk, 0, stream>>>(conv_w4, c4H, c4L, Hd, Hd, 4);

  // ---------------- phase 0: 2 chunks of 256 batches ----------------
  for (int c = 0; c < 2; c++) {
    const int NB = 256;
    const int M96 = NB * Tin;      // 24576
    const int Mpch = NB * Tp;      // 12288
    const int Mfch = NB * Ff;      // 6400
    const float* xc = x + (size_t)c * NB * Tin * DIN;

    gemm3<0, 0, E_BIAS | E_PE><<<dim3(Hd / GBN, M96 / GBM), blk, 0, stream>>>(
        xc, NUS, NUS, WinH, WinL, b_in, pe, A0, nullptr, nullptr,
        M96, Hd, DIN, DIN, Tin, 0, 0, Hd, 0);
    gemm3<1, 0, E_BIAS | E_RES><<<dim3(Hd / GBN, M96 / GBM), blk, 0, stream>>>(
        A0, NUS, NUS, WshH, WshL, b_shape, A0, A2, nullptr, nullptr,
        M96, Hd, Hd, Hd, Tin, 0, 0, Hd, 0);
    gemm3<0, 0, E_BIAS><<<dim3(Hd / GBN, Mpch / GBM), blk, 0, stream>>>(
        A2, NUS, NUS, WpaH, WpaL, b_patch, NF, A0, nullptr, nullptr,
        Mpch, Hd, Pp * Hd, Pp * Hd, 0, 0, 0, Hd, 0);
    rfft48_kernel<<<dim3(Ff, NB), blk, 0, stream>>>(A0, A2);
    float* hrows = A1 + (size_t)c * Mfch * Ed;
    gemm3<0, 0, E_BIAS><<<dim3(Hd / GBN, Mfch / GBM), blk, 0, stream>>>(
        A2, NUS, NUS, c1H, c1L, conv_b1, NF, hrows, nullptr, nullptr,
        Mfch, Hd, Hd, Hd, Ff, 0, 0, Ed, 0);
    gemm3<2, 0, E_BIAS><<<dim3(Hd / GBN, Mfch / GBM), blk, 0, stream>>>(
        A2, NUS, NUS, c2H, c2L, conv_b2, NF, hrows, nullptr, nullptr,
        Mfch, Hd, Hd * 2, Hd, Ff, 0, Hd, Ed, Hd);
    gemm3<2, 0, E_BIAS><<<dim3(Hd / GBN, Mfch / GBM), blk, 0, stream>>>(
        A2, NUS, NUS, c4H, c4L, conv_b4, NF, hrows, nullptr, nullptr,
        Mfch, Hd, Hd * 4, Hd, Ff, 1, Hd, Ed, 2 * Hd);
  }

  // ---------------- transformer layers ----------------
  ushortT* qkH = Wb + 0;        ushortT* qkL = Wb + 1769472;   // [2304][768]
  ushortT* woH = Wb + 3538944;  ushortT* woL = Wb + 4128768;   // [768][768]
  ushortT* f1H = Wb + 0;        ushortT* f1L = Wb + 2359296;   // [3072][768]
  ushortT* f2H = Wb + 4718592;  ushortT* f2L = Wb + 7077888;   // [768][3072]

  const int NBA = 64;            // attention chunk batches (8 chunks)
  const int Mca = NBA * Ff;      // 1600 rows

  for (int l = 0; l < Ll; l++) {
    const float* Wqkv_l = Wqkv + (size_t)l * Ed * (3 * Ed);
    const float* Wo_l   = Wo   + (size_t)l * Ed * Ed;
    const float* bo_l   = bo   + (size_t)l * Ed;
    const float* Wf1_l  = Wf1  + (size_t)l * Ed * (4 * Ed);
    const float* bf1_l  = bf1  + (size_t)l * (4 * Ed);
    const float* Wf2_l  = Wf2  + (size_t)l * (4 * Ed) * Ed;
    const float* bf2_l  = bf2  + (size_t)l * Ed;

    wcvt_t_split<<<dim3((3 * Ed) / 32, Ed / 32), wblk, 0, stream>>>(Wqkv_l, qkH, qkL, Ed, 3 * Ed);
    wcvt_t_split<<<dim3(Ed / 32, Ed / 32), wblk, 0, stream>>>(Wo_l, woH, woL, Ed, Ed);

    ln_split<<<Mf, blk, 0, stream>>>(A1, ln1_g + (size_t)l * Ed, ln1_b + (size_t)l * Ed, Ahp, Alp);

    for (int c = 0; c < 8; c++) {
      ushortT* ah = Ahp + (size_t)c * Mca * Ed;
      ushortT* al = Alp + (size_t)c * Mca * Ed;
      gemm3<0, 1, 0><<<dim3((3 * Ed) / GBN, (Mca + GBM - 1) / GBM), blk, 0, stream>>>(
          NF, ah, al, qkH, qkL, NF, NF, A2, nullptr, nullptr,
          Mca, 3 * Ed, Ed, Ed, 0, 0, 0, 3 * Ed, 0);
      attn_kernel<<<NBA * NHEAD, dim3(128), 0, stream>>>(A2, attnw_ws);
      virfft_kernel<<<NBA * NHEAD, dim3(128), 0, stream>>>(A2, attnw_ws, ah, al);
    }
    gemm3<0, 1, E_BIAS | E_ACC><<<dim3(Ed / GBN, Mf / GBM), blk, 0, stream>>>(
        NF, Ahp, Alp, woH, woL, bo_l, NF, A1, nullptr, nullptr,
        Mf, Ed, Ed, Ed, 0, 0, 0, Ed, 0);

    wcvt_t_split<<<dim3((4 * Ed) / 32, Ed / 32), wblk, 0, stream>>>(Wf1_l, f1H, f1L, Ed, 4 * Ed);
    wcvt_t_split<<<dim3(Ed / 32, (4 * Ed) / 32), wblk, 0, stream>>>(Wf2_l, f2H, f2L, 4 * Ed, Ed);

    ln_split<<<Mf, blk, 0, stream>>>(A1, ln2_g + (size_t)l * Ed, ln2_b + (size_t)l * Ed, Ahp, Alp);

    ushortT* Ch2 = (ushortT*)A2;
    ushortT* Cl2 = Ch2 + 2048 * 3072;
    for (int row0 = 0; row0 < Mf; row0 += 2048) {
      int rows = (Mf - row0 < 2048) ? (Mf - row0) : 2048;
      gemm3<0, 1, E_BIAS | E_GELU | E_OUTS><<<dim3((4 * Ed) / GBN, rows / GBM), blk, 0, stream>>>(
          NF, Ahp + (size_t)row0 * Ed, Alp + (size_t)row0 * Ed, f1H, f1L, bf1_l, NF,
          nullptr, Ch2, Cl2, rows, 4 * Ed, Ed, Ed, 0, 0, 0, 4 * Ed, 0);
      gemm3<0, 1, E_BIAS | E_ACC><<<dim3(Ed / GBN, rows / GBM), blk, 0, stream>>>(
          NF, Ch2, Cl2, f2H, f2L, bf2_l, NF, A1 + (size_t)row0 * Ed, nullptr, nullptr,
          rows, Ed, 4 * Ed, 4 * Ed, 0, 0, 0, Ed, 0);
    }
  }

  // ---------------- tail ----------------
  ushortT* ssH = Wb + 0; ushortT* ssL = Wb + 1769472;
  wcvt_split_tm<<<512, blk, 0, stream>>>(ssm_w, ssH, ssL, Ed, Ed, 3);
  gemm3<2, 0, E_BIAS | E_RES><<<dim3(Ed / GBN, Mf / GBM), blk, 0, stream>>>(
      A1, NUS, NUS, ssH, ssL, ssm_b, A1, A0, nullptr, nullptr,
      Mf, Ed, Ed * 3, Ed, Ff, 1, Ed, Ed, 0);

  ln_f32<<<Mf, blk, 0, stream>>>(A0, ssm_g, ssm_bn, A1);
  mean_kernel<<<Bsz, blk, 0, stream>>>(A1, A2);
  gemm_cls<<<dim3(2, Bsz / BM), blk, 0, stream>>>(
      A2, W_out, b_out, out, Bsz, NCls, Ed, Ed, NCls);
}

// Round 6
// 8126.862 us; speedup vs baseline: 2.0832x; 1.1301x over previous
//
#include <hip/hip_runtime.h>
#include <hip/hip_bf16.h>
#include <math.h>

// ---------------- problem constants ----------------
#define Bsz 512
#define Tin 96
#define DIN 64
#define Hd  256
#define Pp  2
#define Ll  4
#define NHEAD 8
#define Ed  768          // 3*H
#define NCls 100
#define Tp  48           // T/P tokens after patch
#define Ff  25           // rfft freqs of 48
#define F2  13           // rfft freqs of 25
#define DH  96           // E / HEADS

// epilogue flags
#define E_BIAS 1
#define E_PE   2
#define E_RES  4
#define E_ACC  8
#define E_GELU 16
#define E_OUTS 32        // write split hi/lo bf16 planes

typedef unsigned short ushortT;
typedef unsigned short ushort8 __attribute__((ext_vector_type(8)));
typedef short short8 __attribute__((ext_vector_type(8)));
typedef float f32x4 __attribute__((ext_vector_type(4)));

static __device__ __forceinline__ ushortT f2bf(float f) {
  __hip_bfloat16 h = __float2bfloat16(f);
  return *reinterpret_cast<ushortT*>(&h);
}
static __device__ __forceinline__ float bfbits2f(ushortT u) {
  unsigned int x = ((unsigned int)u) << 16;
  return __uint_as_float(x);
}
static __device__ __forceinline__ void split2(float v, ushortT& h, ushortT& l) {
  h = f2bf(v);
  l = f2bf(v - bfbits2f(h));
}

// =================== bf16x3 split MFMA GEMM ===================
// AMODE: 0 plain; 1 diff along Tdim; 2 tap-major conv (K=(tap,i), Kin inner)
// ASRC:  0 A fp32 [M,K]; 1 A pre-split planes Ah/Al [M,K] bf16
// Grid: 1D = Mt*Nt with XCD-aware swizzle (xcd = lin&7 round-robin; each XCD
// owns a contiguous tile-index range enumerated major on the larger operand).
constexpr int GBM = 128, GBN = 128, GBK = 32, LDK = GBK + 8;

template<int AMODE, int ASRC, int EPI>
__global__ __launch_bounds__(256) void gemm3(
    const float* __restrict__ A,
    const ushortT* __restrict__ Ah, const ushortT* __restrict__ Al,
    const ushortT* __restrict__ Bh, const ushortT* __restrict__ Bl,
    const float* __restrict__ bias, const float* __restrict__ extra,
    float* __restrict__ C, ushortT* __restrict__ Coh, ushortT* __restrict__ Col,
    int M, int N, int K, int Ald, int Tdim, int lo, int Kin, int Cld, int coff,
    int Mt, int Nt, int mmaj)
{
  __shared__ ushortT Ash[GBM * LDK];
  __shared__ ushortT Asl[GBM * LDK];
  __shared__ ushortT Bsh[GBN * LDK];
  __shared__ ushortT Bsl[GBN * LDK];
  int tid = threadIdx.x;

  int lin = blockIdx.x;
  int G = gridDim.x;
  int r = lin & 7, s = lin >> 3;
  int q = G >> 3, rem = G & 7;
  int start = r * q + (r < rem ? r : rem);
  int idx = start + s;
  int mt, nt;
  if (mmaj) { mt = idx / Nt; nt = idx - mt * Nt; }
  else      { nt = idx / Mt; mt = idx - nt * Mt; }
  int m0 = mt * GBM, n0 = nt * GBN;

  int wid = tid >> 6, lane = tid & 63;
  int wm = wid & 1, wn = wid >> 1;
  int m16 = lane & 15, quad = lane >> 4;

  f32x4 acc[4][4] = {};

  int srow = tid >> 1;           // 0..127
  int skh  = (tid & 1) * 16;     // 0 or 16

  for (int k0 = 0; k0 < K; k0 += GBK) {
    // ---- stage A ----
    {
      int row = m0 + srow;
      if (row >= M) row = M - 1;
      if (ASRC == 1) {
        size_t aoff = (size_t)row * Ald + k0 + skh;
        *(uint4*)&Ash[srow * LDK + skh]     = *(const uint4*)(Ah + aoff);
        *(uint4*)&Ash[srow * LDK + skh + 8] = *(const uint4*)(Ah + aoff + 8);
        *(uint4*)&Asl[srow * LDK + skh]     = *(const uint4*)(Al + aoff);
        *(uint4*)&Asl[srow * LDK + skh + 8] = *(const uint4*)(Al + aoff + 8);
      } else {
        float tf[16];
        if (AMODE == 0) {
          const float* p = A + (size_t)row * Ald + k0 + skh;
#pragma unroll
          for (int j = 0; j < 16; j += 4) {
            float4 v = *(const float4*)(p + j);
            tf[j] = v.x; tf[j+1] = v.y; tf[j+2] = v.z; tf[j+3] = v.w;
          }
        } else if (AMODE == 1) {
          int t = row % Tdim;
          const float* p = A + (size_t)row * Ald + k0 + skh;
#pragma unroll
          for (int j = 0; j < 16; j += 4) {
            float4 v = *(const float4*)(p + j);
            float4 w = (t != 0) ? *(const float4*)(p - Ald + j) : v;
            tf[j] = v.x - w.x; tf[j+1] = v.y - w.y;
            tf[j+2] = v.z - w.z; tf[j+3] = v.w - w.w;
          }
        } else {   // tap-major conv; tap uniform over this 16-seg
          int kk = k0 + skh;
          int tap = kk / Kin;
          int i0  = kk - tap * Kin;
          int bb = row / Tdim;
          int t  = row - bb * Tdim;
          int tt = t - lo + tap;
          if (tt >= 0 && tt < Tdim) {
            const float* p = A + ((size_t)bb * Tdim + tt) * Ald + i0;
#pragma unroll
            for (int j = 0; j < 16; j += 4) {
              float4 v = *(const float4*)(p + j);
              tf[j] = v.x; tf[j+1] = v.y; tf[j+2] = v.z; tf[j+3] = v.w;
            }
          } else {
#pragma unroll
            for (int j = 0; j < 16; j++) tf[j] = 0.0f;
          }
        }
        ushortT th[16], tl[16];
#pragma unroll
        for (int j = 0; j < 16; j++) split2(tf[j], th[j], tl[j]);
        *(ushort8*)&Ash[srow * LDK + skh]     = *(ushort8*)&th[0];
        *(ushort8*)&Ash[srow * LDK + skh + 8] = *(ushort8*)&th[8];
        *(ushort8*)&Asl[srow * LDK + skh]     = *(ushort8*)&tl[0];
        *(ushort8*)&Asl[srow * LDK + skh + 8] = *(ushort8*)&tl[8];
      }
    }
    // ---- stage B hi/lo ----
    {
      size_t boff = (size_t)(n0 + srow) * K + k0 + skh;
      *(uint4*)&Bsh[srow * LDK + skh]     = *(const uint4*)(Bh + boff);
      *(uint4*)&Bsh[srow * LDK + skh + 8] = *(const uint4*)(Bh + boff + 8);
      *(uint4*)&Bsl[srow * LDK + skh]     = *(const uint4*)(Bl + boff);
      *(uint4*)&Bsl[srow * LDK + skh + 8] = *(const uint4*)(Bl + boff + 8);
    }
    __syncthreads();
    short8 ah[4], al[4], bh[4], bl[4];
#pragma unroll
    for (int i = 0; i < 4; i++) {
      int ro = (wm * 64 + i * 16 + m16) * LDK + quad * 8;
      ah[i] = *(short8*)&Ash[ro];
      al[i] = *(short8*)&Asl[ro];
    }
#pragma unroll
    for (int j = 0; j < 4; j++) {
      int ro = (wn * 64 + j * 16 + m16) * LDK + quad * 8;
      bh[j] = *(short8*)&Bsh[ro];
      bl[j] = *(short8*)&Bsl[ro];
    }
#pragma unroll
    for (int i = 0; i < 4; i++)
#pragma unroll
      for (int j = 0; j < 4; j++) {
        acc[i][j] = __builtin_amdgcn_mfma_f32_16x16x32_bf16(ah[i], bh[j], acc[i][j], 0, 0, 0);
        acc[i][j] = __builtin_amdgcn_mfma_f32_16x16x32_bf16(al[i], bh[j], acc[i][j], 0, 0, 0);
        acc[i][j] = __builtin_amdgcn_mfma_f32_16x16x32_bf16(ah[i], bl[j], acc[i][j], 0, 0, 0);
      }
    __syncthreads();
  }

  // ---- epilogue: C/D map col=lane&15, row=quad*4+r ----
#pragma unroll
  for (int i = 0; i < 4; i++) {
#pragma unroll
    for (int j = 0; j < 4; j++) {
      int colg = n0 + wn * 64 + j * 16 + m16;
#pragma unroll
      for (int rr = 0; rr < 4; rr++) {
        int rowg = m0 + wm * 64 + i * 16 + quad * 4 + rr;
        if (rowg >= M) continue;
        float v = acc[i][j][rr];
        if (EPI & E_BIAS) v += bias[colg];
        if (EPI & E_PE)   v += extra[(size_t)(rowg % Tdim) * N + colg];
        if (EPI & E_RES)  v += extra[(size_t)rowg * Cld + colg];
        if (EPI & E_GELU) v = 0.5f * v * (1.0f + erff(v * 0.70710678118654752f));
        size_t off = (size_t)rowg * Cld + coff + colg;
        if (EPI & E_OUTS) {
          ushortT h, l; split2(v, h, l);
          Coh[off] = h; Col[off] = l;
        } else {
          if (EPI & E_ACC) v += C[off];
          C[off] = v;
        }
      }
    }
  }
}

#define GEMM3(AM, AS, EP, Asrc, AhP, AlP, BhP, BlP, biasP, extraP, CP, CohP, ColP, \
              Mv, Nv, Kv, AldV, TdimV, loV, KinV, CldV, coffV) \
  do { int Mt_ = (Mv) / GBM, Nt_ = (Nv) / GBN; int mm_ = ((Mv) >= (Nv)) ? 1 : 0; \
       gemm3<AM, AS, EP><<<dim3(Mt_ * Nt_), dim3(256), 0, stream>>>( \
           Asrc, AhP, AlP, BhP, BlP, biasP, extraP, CP, CohP, ColP, \
           Mv, Nv, Kv, AldV, TdimV, loV, KinV, CldV, coffV, Mt_, Nt_, mm_); } while (0)

// ====== weight transpose + split: fp32 [K][N] -> bf16 hi/lo [N][K] ======
__global__ __launch_bounds__(256) void wcvt_t_split(
    const float* __restrict__ W, ushortT* __restrict__ Wh, ushortT* __restrict__ Wl,
    int K, int N)
{
  __shared__ float t[32][33];
  int k0 = blockIdx.y * 32, n0 = blockIdx.x * 32;
  int tx = threadIdx.x;
  int ty = threadIdx.y;
#pragma unroll
  for (int dy = 0; dy < 32; dy += 8)
    t[ty + dy][tx] = W[(size_t)(k0 + ty + dy) * N + n0 + tx];
  __syncthreads();
#pragma unroll
  for (int dy = 0; dy < 32; dy += 8) {
    float v = t[tx][ty + dy];
    ushortT h, l;
    split2(v, h, l);
    size_t off = (size_t)(n0 + ty + dy) * K + k0 + tx;
    Wh[off] = h; Wl[off] = l;
  }
}

// ====== flat split: fp32 -> bf16 hi/lo ======
__global__ __launch_bounds__(256) void wcvt_split(
    const float* __restrict__ W, ushortT* __restrict__ Wh, ushortT* __restrict__ Wl, int n)
{
  int gid = blockIdx.x * 256 + threadIdx.x;
  int stride = gridDim.x * 256;
  for (int i = gid; i < n; i += stride) {
    ushortT h, l;
    split2(W[i], h, l);
    Wh[i] = h; Wl[i] = l;
  }
}

// ====== conv weight split, tap-major: [O][Kin][NT] -> [O][NT*Kin] ======
__global__ __launch_bounds__(256) void wcvt_split_tm(
    const float* __restrict__ W, ushortT* __restrict__ Wh, ushortT* __restrict__ Wl,
    int O, int Kin, int NT)
{
  int n = O * Kin * NT;
  int gid = blockIdx.x * 256 + threadIdx.x;
  int stride = gridDim.x * 256;
  for (int idx = gid; idx < n; idx += stride) {
    int o = idx / (Kin * NT);
    int rr = idx - o * (Kin * NT);
    int tap = rr / Kin;
    int i = rr - tap * Kin;
    float v = W[(size_t)o * Kin * NT + (size_t)i * NT + tap];
    ushortT h, l;
    split2(v, h, l);
    Wh[idx] = h; Wl[idx] = l;
  }
}

// =================== fp32 fallback GEMM (classifier only) ===================
constexpr int BM = 64, BN = 64, BK = 16, TM = 4, TN = 4;
__global__ __launch_bounds__(256) void gemm_cls(
    const float* __restrict__ A, const float* __restrict__ Bw,
    const float* __restrict__ bias, float* __restrict__ C,
    int M, int N, int K, int Ald, int Cld)
{
  __shared__ alignas(16) float As[BK][BM + 4];
  __shared__ alignas(16) float Bs[BK][BN + 4];
  int tid = threadIdx.x;
  int n0 = blockIdx.x * BN;
  int m0 = blockIdx.y * BM;
  int tx = tid & 15, ty = tid >> 4;
  float acc[TM][TN];
#pragma unroll
  for (int i = 0; i < TM; i++)
#pragma unroll
    for (int j = 0; j < TN; j++) acc[i][j] = 0.0f;
  int a_m = tid >> 2, a_k = (tid & 3) * 4;
  int b_k = tid >> 4, b_n = (tid & 15) * 4;
  for (int k0 = 0; k0 < K; k0 += BK) {
    int row = m0 + a_m;
#pragma unroll
    for (int j = 0; j < 4; j++)
      As[a_k + j][a_m] = A[(size_t)row * Ald + k0 + a_k + j];
    int kk = k0 + b_k;
#pragma unroll
    for (int j = 0; j < 4; j++) {
      int nn = n0 + b_n + j;
      Bs[b_k][b_n + j] = (nn < N) ? Bw[(size_t)kk * N + nn] : 0.0f;
    }
    __syncthreads();
#pragma unroll
    for (int k = 0; k < BK; k++) {
      float4 av = *reinterpret_cast<const float4*>(&As[k][ty * TM]);
      float4 bv = *reinterpret_cast<const float4*>(&Bs[k][tx * TN]);
      float a4[4] = {av.x, av.y, av.z, av.w};
      float b4[4] = {bv.x, bv.y, bv.z, bv.w};
#pragma unroll
      for (int i = 0; i < TM; i++)
#pragma unroll
        for (int j = 0; j < TN; j++) acc[i][j] += a4[i] * b4[j];
    }
    __syncthreads();
  }
#pragma unroll
  for (int i = 0; i < TM; i++) {
    int row = m0 + ty * TM + i;
#pragma unroll
    for (int j = 0; j < TN; j++) {
      int col = n0 + tx * TN + j;
      if (col >= N) continue;
      C[(size_t)row * Cld + col] = acc[i][j] + bias[col];
    }
  }
}

// ---- rfft over 48 tokens, real part (fp32) ----
__global__ __launch_bounds__(256) void rfft48_kernel(
    const float* __restrict__ hp, float* __restrict__ f)
{
  int kf = blockIdx.x;
  int b  = blockIdx.y;
  int tid = threadIdx.x;
  __shared__ float ct[48];
  if (tid < 48) {
    int rr = (kf * tid) % 48;
    ct[tid] = cosf(6.2831853071795864f * (float)rr / 48.0f);
  }
  __syncthreads();
  const float* hb = hp + (size_t)b * Tp * Hd;
  float s = 0.0f;
  for (int t = 0; t < 48; t++) s += hb[t * Hd + tid] * ct[t];
  f[((size_t)b * Ff + kf) * Hd + tid] = s;
}

// ---- fused fourier attention: logits -> softmax -> circulant(G) @ v ----
// irfft(attn * vf)[t] = sum_t' v[t'] * G[(t-t') mod 25],
// G[d] = sum_fq attn[fq] * w_fq * cos(2pi*fq*d/25), w_0=1/25 else 2/25.
__global__ __launch_bounds__(256) void attn_fused(
    const float* __restrict__ qkv,     // chunk [nb*25, 2304]
    ushortT* __restrict__ oh, ushortT* __restrict__ ol)
{
  int bh = blockIdx.x;
  int b = bh >> 3, h = bh & 7;
  __shared__ float qs[Ff * DH], ks[Ff * DH], vs[Ff * DH];
  __shared__ float ct[F2 * Ff], st[F2 * Ff];
  __shared__ float red[F2 * DH];
  __shared__ float sm[F2];
  __shared__ float G[Ff];
  int tid = threadIdx.x;
  const float* base = qkv + (size_t)b * Ff * (3 * Ed) + h * DH;
  for (int e = tid; e < Ff * DH; e += 256) {
    int t = e / DH, d = e - t * DH;
    size_t ro = (size_t)t * (3 * Ed) + d;
    qs[e] = base[ro];
    ks[e] = base[ro + Ed];
    vs[e] = base[ro + 2 * Ed];
  }
  for (int e = tid; e < F2 * Ff; e += 256) {
    int fq = e / Ff, t = e - fq * Ff;
    int rr = (fq * t) % Ff;
    float ang = 6.2831853071795864f * (float)rr / 25.0f;
    ct[e] = cosf(ang); st[e] = sinf(ang);
  }
  __syncthreads();
  for (int e = tid; e < F2 * DH; e += 256) {
    int fq = e / DH, d = e - fq * DH;
    float qr = 0, qi = 0, kr = 0, ki = 0;
    for (int t = 0; t < Ff; t++) {
      float c = ct[fq * Ff + t], s = st[fq * Ff + t];
      float qv = qs[t * DH + d], kv = ks[t * DH + d];
      qr += qv * c; qi += qv * s; kr += kv * c; ki += kv * s;
    }
    red[e] = qr * kr + qi * ki;
  }
  __syncthreads();
  if (tid < F2) {
    float s = 0;
    for (int d = 0; d < DH; d++) s += red[tid * DH + d];
    sm[tid] = s * 0.10206207261596575f;  // 96^-0.5
  }
  __syncthreads();
  if (tid == 0) {
    float mx = sm[0];
    for (int f = 1; f < F2; f++) mx = fmaxf(mx, sm[f]);
    float den = 0;
    for (int f = 0; f < F2; f++) { float e2 = expf(sm[f] - mx); sm[f] = e2; den += e2; }
    float inv = 1.0f / den;
    for (int f = 0; f < F2; f++)
      sm[f] *= inv * ((f == 0) ? (1.0f / 25.0f) : (2.0f / 25.0f));
  }
  __syncthreads();
  if (tid < Ff) {
    float g = 0;
    for (int f = 0; f < F2; f++) g += sm[f] * ct[f * Ff + tid];
    G[tid] = g;
  }
  __syncthreads();
  size_t ob = ((size_t)b * Ff) * Ed + h * DH;
  for (int e = tid; e < Ff * DH; e += 256) {
    int t = e / DH, d = e - t * DH;
    float o = 0;
    int dd = t;
    for (int tp = 0; tp < Ff; tp++) {
      o += G[dd] * vs[tp * DH + d];
      dd--; if (dd < 0) dd += Ff;
    }
    ushortT hh, ll;
    split2(o, hh, ll);
    size_t off = ob + (size_t)t * Ed + d;
    oh[off] = hh; ol[off] = ll;
  }
}

// ---- layernorm over 768, split bf16 out ----
__global__ __launch_bounds__(256) void ln_split(
    const float* __restrict__ x, const float* __restrict__ g,
    const float* __restrict__ bb, ushortT* __restrict__ yh, ushortT* __restrict__ yl)
{
  int row = blockIdx.x;
  int tid = threadIdx.x;
  const float* xr = x + (size_t)row * Ed;
  float v0 = xr[tid], v1 = xr[tid + 256], v2 = xr[tid + 512];
  __shared__ float rs[256];
  rs[tid] = v0 + v1 + v2;
  __syncthreads();
  for (int o = 128; o > 0; o >>= 1) {
    if (tid < o) rs[tid] += rs[tid + o];
    __syncthreads();
  }
  float m = rs[0] * (1.0f / 768.0f);
  __syncthreads();
  float d0 = v0 - m, d1 = v1 - m, d2 = v2 - m;
  rs[tid] = d0 * d0 + d1 * d1 + d2 * d2;
  __syncthreads();
  for (int o = 128; o > 0; o >>= 1) {
    if (tid < o) rs[tid] += rs[tid + o];
    __syncthreads();
  }
  float inv = rsqrtf(rs[0] * (1.0f / 768.0f) + 1e-5f);
  size_t basei = (size_t)row * Ed;
  float o0 = d0 * inv * g[tid] + bb[tid];
  float o1 = d1 * inv * g[tid + 256] + bb[tid + 256];
  float o2 = d2 * inv * g[tid + 512] + bb[tid + 512];
  ushortT h, l;
  split2(o0, h, l); yh[basei + tid] = h;       yl[basei + tid] = l;
  split2(o1, h, l); yh[basei + tid + 256] = h; yl[basei + tid + 256] = l;
  split2(o2, h, l); yh[basei + tid + 512] = h; yl[basei + tid + 512] = l;
}

// ---- layernorm over 768, fp32 out (final) ----
__global__ __launch_bounds__(256) void ln_f32(
    const float* __restrict__ x, const float* __restrict__ g,
    const float* __restrict__ bb, float* __restrict__ y)
{
  int row = blockIdx.x;
  int tid = threadIdx.x;
  const float* xr = x + (size_t)row * Ed;
  float v0 = xr[tid], v1 = xr[tid + 256], v2 = xr[tid + 512];
  __shared__ float rs[256];
  rs[tid] = v0 + v1 + v2;
  __syncthreads();
  for (int o = 128; o > 0; o >>= 1) {
    if (tid < o) rs[tid] += rs[tid + o];
    __syncthreads();
  }
  float m = rs[0] * (1.0f / 768.0f);
  __syncthreads();
  float d0 = v0 - m, d1 = v1 - m, d2 = v2 - m;
  rs[tid] = d0 * d0 + d1 * d1 + d2 * d2;
  __syncthreads();
  for (int o = 128; o > 0; o >>= 1) {
    if (tid < o) rs[tid] += rs[tid + o];
    __syncthreads();
  }
  float inv = rsqrtf(rs[0] * (1.0f / 768.0f) + 1e-5f);
  float* yr = y + (size_t)row * Ed;
  yr[tid]       = d0 * inv * g[tid]       + bb[tid];
  yr[tid + 256] = d1 * inv * g[tid + 256] + bb[tid + 256];
  yr[tid + 512] = d2 * inv * g[tid + 512] + bb[tid + 512];
}

// ---- mean over 25 tokens ----
__global__ __launch_bounds__(256) void mean_kernel(
    const float* __restrict__ x, float* __restrict__ y)
{
  int b = blockIdx.x;
  int tid = threadIdx.x;
  for (int c = tid; c < Ed; c += 256) {
    float s = 0;
    for (int t = 0; t < Ff; t++) s += x[((size_t)b * Ff + t) * Ed + c];
    y[(size_t)b * Ed + c] = s * (1.0f / 25.0f);
  }
}

extern "C" void kernel_launch(void* const* d_in, const int* in_sizes, int n_in,
                              void* d_out, int out_size, void* d_ws, size_t ws_size,
                              hipStream_t stream)
{
  const float* x       = (const float*)d_in[0];
  const float* W_in    = (const float*)d_in[1];
  const float* b_in    = (const float*)d_in[2];
  const float* pe      = (const float*)d_in[3];
  const float* W_shape = (const float*)d_in[4];
  const float* b_shape = (const float*)d_in[5];
  const float* W_patch = (const float*)d_in[6];
  const float* b_patch = (const float*)d_in[7];
  const float* conv_w1 = (const float*)d_in[8];
  const float* conv_b1 = (const float*)d_in[9];
  const float* conv_w2 = (const float*)d_in[10];
  const float* conv_b2 = (const float*)d_in[11];
  const float* conv_w4 = (const float*)d_in[12];
  const float* conv_b4 = (const float*)d_in[13];
  const float* ln1_g   = (const float*)d_in[14];
  const float* ln1_b   = (const float*)d_in[15];
  const float* Wqkv    = (const float*)d_in[16];
  const float* Wo      = (const float*)d_in[17];
  const float* bo      = (const float*)d_in[18];
  const float* ln2_g   = (const float*)d_in[19];
  const float* ln2_b   = (const float*)d_in[20];
  const float* Wf1     = (const float*)d_in[21];
  const float* bf1     = (const float*)d_in[22];
  const float* Wf2     = (const float*)d_in[23];
  const float* bf2     = (const float*)d_in[24];
  const float* ssm_w   = (const float*)d_in[25];
  const float* ssm_b   = (const float*)d_in[26];
  const float* ssm_g   = (const float*)d_in[27];
  const float* ssm_bn  = (const float*)d_in[28];
  const float* W_out   = (const float*)d_in[29];
  const float* b_out   = (const float*)d_in[30];
  float* out = (float*)d_out;

  // ---- workspace: h 39.3MB | planes 39.3MB | pool 44.0MB = 122.7MB ----
  float* hbuf = (float*)d_ws;                    // 9,830,400 fl
  ushortT* Ahp = (ushortT*)(hbuf + 9830400);     // 9,830,400 slots
  ushortT* Alp = Ahp + 9830400;                  // 9,830,400 slots
  float* pool = (float*)(Alp + 9830400);         // 11,010,048 fl

  dim3 blk(256);
  dim3 wblk(32, 8);
  const int Mf = Bsz * Ff;   // 12800
  const ushortT* NUS = nullptr;
  const float* NF = nullptr;
  ushortT* NU = nullptr;

  // ---------------- phase-0 weights (pool + 6,291,456 fl) ----------------
  ushortT* p0w = (ushortT*)(pool + 6291456);
  ushortT* WinH = p0w + 0;        ushortT* WinL = p0w + 16384;
  ushortT* WshH = p0w + 32768;    ushortT* WshL = p0w + 98304;
  ushortT* WpaH = p0w + 163840;   ushortT* WpaL = p0w + 294912;
  ushortT* c1H  = p0w + 425984;   ushortT* c1L  = p0w + 491520;
  ushortT* c2H  = p0w + 557056;   ushortT* c2L  = p0w + 688128;
  ushortT* c4H  = p0w + 819200;   ushortT* c4L  = p0w + 1081344;
  wcvt_t_split<<<dim3(Hd / 32, DIN / 32), wblk, 0, stream>>>(W_in, WinH, WinL, DIN, Hd);
  wcvt_t_split<<<dim3(Hd / 32, Hd / 32), wblk, 0, stream>>>(W_shape, WshH, WshL, Hd, Hd);
  wcvt_t_split<<<dim3(Hd / 32, (Pp * Hd) / 32), wblk, 0, stream>>>(W_patch, WpaH, WpaL, Pp * Hd, Hd);
  wcvt_split<<<64, blk, 0, stream>>>(conv_w1, c1H, c1L, Hd * Hd);
  wcvt_split_tm<<<128, blk, 0, stream>>>(conv_w2, c2H, c2L, Hd, Hd, 2);
  wcvt_split_tm<<<256, blk, 0, stream>>>(conv_w4, c4H, c4L, Hd, Hd, 4);

  // ---------------- phase 0: 2 chunks of 256 batches ----------------
  float* s0 = (float*)Ahp;   // scratch0 in plane area (39.3MB)
  float* s1 = pool;          // scratch1 (25.2MB)
  for (int c = 0; c < 2; c++) {
    const int NB = 256;
    const int M96 = NB * Tin;      // 24576
    const int Mpch = NB * Tp;      // 12288
    const int Mfch = NB * Ff;      // 6400
    const float* xc = x + (size_t)c * NB * Tin * DIN;

    GEMM3(0, 0, E_BIAS | E_PE, xc, NUS, NUS, WinH, WinL, b_in, pe, s0, NU, NU,
          M96, Hd, DIN, DIN, Tin, 0, 0, Hd, 0);
    GEMM3(1, 0, E_BIAS | E_RES, s0, NUS, NUS, WshH, WshL, b_shape, s0, s1, NU, NU,
          M96, Hd, Hd, Hd, Tin, 0, 0, Hd, 0);
    GEMM3(0, 0, E_BIAS, s1, NUS, NUS, WpaH, WpaL, b_patch, NF, s0, NU, NU,
          Mpch, Hd, Pp * Hd, Pp * Hd, 0, 0, 0, Hd, 0);
    rfft48_kernel<<<dim3(Ff, NB), blk, 0, stream>>>(s0, s1);
    float* hrows = hbuf + (size_t)c * Mfch * Ed;
    GEMM3(0, 0, E_BIAS, s1, NUS, NUS, c1H, c1L, conv_b1, NF, hrows, NU, NU,
          Mfch, Hd, Hd, Hd, Ff, 0, 0, Ed, 0);
    GEMM3(2, 0, E_BIAS, s1, NUS, NUS, c2H, c2L, conv_b2, NF, hrows, NU, NU,
          Mfch, Hd, Hd * 2, Hd, Ff, 0, Hd, Ed, Hd);
    GEMM3(2, 0, E_BIAS, s1, NUS, NUS, c4H, c4L, conv_b4, NF, hrows, NU, NU,
          Mfch, Hd, Hd * 4, Hd, Ff, 1, Hd, Ed, 2 * Hd);
  }

  // ---------------- transformer layers ----------------
  float* qkvbuf = pool;                          // 7,372,800 fl (chunk 3200x2304)
  ushortT* lwA = (ushortT*)(pool + 7372800);
  ushortT* qkH = lwA + 0;        ushortT* qkL = lwA + 1769472;
  ushortT* woH = lwA + 3538944;  ushortT* woL = lwA + 4128768;
  ushortT* Ch2 = (ushortT*)pool;                 // ffmid hi (2048x3072)
  ushortT* Cl2 = Ch2 + 6291456;                  // ffmid lo
  ushortT* lwB = (ushortT*)(pool + 6291456);
  ushortT* f1H = lwB + 0;        ushortT* f1L = lwB + 2359296;
  ushortT* f2H = lwB + 4718592;  ushortT* f2L = lwB + 7077888;

  const int NBA = 128;           // batches per attention chunk (4 chunks)
  const int Mca = NBA * Ff;      // 3200 rows

  for (int l = 0; l < Ll; l++) {
    const float* Wqkv_l = Wqkv + (size_t)l * Ed * (3 * Ed);
    const float* Wo_l   = Wo   + (size_t)l * Ed * Ed;
    const float* bo_l   = bo   + (size_t)l * Ed;
    const float* Wf1_l  = Wf1  + (size_t)l * Ed * (4 * Ed);
    const float* bf1_l  = bf1  + (size_t)l * (4 * Ed);
    const float* Wf2_l  = Wf2  + (size_t)l * (4 * Ed) * Ed;
    const float* bf2_l  = bf2  + (size_t)l * Ed;

    wcvt_t_split<<<dim3((3 * Ed) / 32, Ed / 32), wblk, 0, stream>>>(Wqkv_l, qkH, qkL, Ed, 3 * Ed);
    wcvt_t_split<<<dim3(Ed / 32, Ed / 32), wblk, 0, stream>>>(Wo_l, woH, woL, Ed, Ed);

    ln_split<<<Mf, blk, 0, stream>>>(hbuf, ln1_g + (size_t)l * Ed, ln1_b + (size_t)l * Ed, Ahp, Alp);

    for (int c = 0; c < 4; c++) {
      ushortT* ah = Ahp + (size_t)c * Mca * Ed;
      ushortT* al = Alp + (size_t)c * Mca * Ed;
      GEMM3(0, 1, 0, NF, ah, al, qkH, qkL, NF, NF, qkvbuf, NU, NU,
            Mca, 3 * Ed, Ed, Ed, 0, 0, 0, 3 * Ed, 0);
      attn_fused<<<NBA * NHEAD, blk, 0, stream>>>(qkvbuf, ah, al);
    }
    GEMM3(0, 1, E_BIAS | E_ACC, NF, Ahp, Alp, woH, woL, bo_l, NF, hbuf, NU, NU,
          Mf, Ed, Ed, Ed, 0, 0, 0, Ed, 0);

    wcvt_t_split<<<dim3((4 * Ed) / 32, Ed / 32), wblk, 0, stream>>>(Wf1_l, f1H, f1L, Ed, 4 * Ed);
    wcvt_t_split<<<dim3(Ed / 32, (4 * Ed) / 32), wblk, 0, stream>>>(Wf2_l, f2H, f2L, 4 * Ed, Ed);

    ln_split<<<Mf, blk, 0, stream>>>(hbuf, ln2_g + (size_t)l * Ed, ln2_b + (size_t)l * Ed, Ahp, Alp);

    for (int row0 = 0; row0 < Mf; row0 += 2048) {
      int rows = (Mf - row0 < 2048) ? (Mf - row0) : 2048;
      GEMM3(0, 1, E_BIAS | E_GELU | E_OUTS, NF,
            Ahp + (size_t)row0 * Ed, Alp + (size_t)row0 * Ed, f1H, f1L, bf1_l, NF,
            (float*)nullptr, Ch2, Cl2, rows, 4 * Ed, Ed, Ed, 0, 0, 0, 4 * Ed, 0);
      GEMM3(0, 1, E_BIAS | E_ACC, NF, Ch2, Cl2, f2H, f2L, bf2_l, NF,
            hbuf + (size_t)row0 * Ed, NU, NU, rows, Ed, 4 * Ed, 4 * Ed, 0, 0, 0, Ed, 0);
    }
  }

  // ---------------- tail ----------------
  ushortT* ssH = (ushortT*)pool; ushortT* ssL = ssH + 1769472;
  wcvt_split_tm<<<512, blk, 0, stream>>>(ssm_w, ssH, ssL, Ed, Ed, 3);
  float* S = (float*)Ahp;   // h + s (plane area)
  GEMM3(2, 0, E_BIAS | E_RES, hbuf, NUS, NUS, ssH, ssL, ssm_b, hbuf, S, NU, NU,
        Mf, Ed, Ed * 3, Ed, Ff, 1, Ed, Ed, 0);

  float* L = pool;          // final LN out (overwrites ssH, dead)
  ln_f32<<<Mf, blk, 0, stream>>>(S, ssm_g, ssm_bn, L);
  float* mout = (float*)Ahp;
  mean_kernel<<<Bsz, blk, 0, stream>>>(L, mout);
  gemm_cls<<<dim3(2, Bsz / BM), blk, 0, stream>>>(
      mout, W_out, b_out, out, Bsz, NCls, Ed, Ed, NCls);
}